// Round 1
// baseline (4140.779 us; speedup 1.0000x reference)
//
#include <hip/hip_runtime.h>

#define N_NODES 100000
#define NNZ_C   600000
#define F_INC   256
#define HIDC    128

__device__ __forceinline__ void atomAddF(float* p, float v) {
    unsafeAtomicAdd(p, v);   // hardware global_atomic_add_f32 on gfx950
}

// ---------------- degree histograms -----------------------------------------
__global__ __launch_bounds__(256) void degrees_kernel(
    const int* __restrict__ nidx, const int* __restrict__ eidx,
    int* __restrict__ cd, int* __restrict__ cb, int nnz)
{
    int i = blockIdx.x * 256 + threadIdx.x;
    if (i < nnz) {
        atomicAdd(&cd[nidx[i]], 1);
        atomicAdd(&cb[eidx[i]], 1);
    }
}

__global__ __launch_bounds__(256) void make_inv_kernel(
    const int* __restrict__ cd, const int* __restrict__ cb,
    float* __restrict__ dinv, float* __restrict__ binv, int n)
{
    int i = blockIdx.x * 256 + threadIdx.x;
    if (i < n) {
        int d = cd[i], b = cb[i];
        dinv[i] = d > 0 ? 1.0f / (float)d : 0.0f;
        binv[i] = b > 0 ? 1.0f / (float)b : 0.0f;
    }
}

// ---------------- fp32 GEMM: C[M,128] = A[M,KDIM] @ W[KDIM,128] -------------
// 128x128 tile / block of 256 threads; each thread 4 rows x 16 cols.
template<int KDIM>
__global__ __launch_bounds__(256) void gemm_f32(
    const float* __restrict__ A, const float* __restrict__ W,
    float* __restrict__ C, int M)
{
    __shared__ float As[128][33];
    __shared__ float Ws[32][128];
    const int tid  = threadIdx.x;
    const int row0 = blockIdx.x * 128;
    const int cg   = tid & 7;    // col group: cols cg*16 .. cg*16+15
    const int rg   = tid >> 3;   // row group: rows rg*4 .. rg*4+3
    const int rbase = rg * 4;
    const int cbase = cg * 16;

    float acc[4][16];
#pragma unroll
    for (int i = 0; i < 4; i++)
#pragma unroll
        for (int j = 0; j < 16; j++) acc[i][j] = 0.0f;

    for (int k0 = 0; k0 < KDIM; k0 += 32) {
        __syncthreads();
        // stage A tile: 128 rows x 32 k  (4096 elems / 256 thr = 16 each)
#pragma unroll
        for (int i = 0; i < 16; i++) {
            int e = tid + i * 256;
            int r = e >> 5, kk = e & 31;
            int grow = row0 + r;
            As[r][kk] = (grow < M) ? A[(size_t)grow * KDIM + k0 + kk] : 0.0f;
        }
        // stage W tile: 32 k x 128 cols
#pragma unroll
        for (int i = 0; i < 16; i++) {
            int e = tid + i * 256;
            int kk = e >> 7, c = e & 127;
            Ws[kk][c] = W[(size_t)(k0 + kk) * 128 + c];
        }
        __syncthreads();
#pragma unroll
        for (int kk = 0; kk < 32; kk++) {
            float a0 = As[rbase + 0][kk];
            float a1 = As[rbase + 1][kk];
            float a2 = As[rbase + 2][kk];
            float a3 = As[rbase + 3][kk];
#pragma unroll
            for (int q = 0; q < 4; q++) {
                const float4 w = *(const float4*)&Ws[kk][cbase + q * 4];
                acc[0][q*4+0] += a0 * w.x; acc[0][q*4+1] += a0 * w.y;
                acc[0][q*4+2] += a0 * w.z; acc[0][q*4+3] += a0 * w.w;
                acc[1][q*4+0] += a1 * w.x; acc[1][q*4+1] += a1 * w.y;
                acc[1][q*4+2] += a1 * w.z; acc[1][q*4+3] += a1 * w.w;
                acc[2][q*4+0] += a2 * w.x; acc[2][q*4+1] += a2 * w.y;
                acc[2][q*4+2] += a2 * w.z; acc[2][q*4+3] += a2 * w.w;
                acc[3][q*4+0] += a3 * w.x; acc[3][q*4+1] += a3 * w.y;
                acc[3][q*4+2] += a3 * w.z; acc[3][q*4+3] += a3 * w.w;
            }
        }
    }
#pragma unroll
    for (int i = 0; i < 4; i++) {
        int grow = row0 + rbase + i;
        if (grow < M) {
#pragma unroll
            for (int q = 0; q < 4; q++) {
                float4 v = make_float4(acc[i][q*4+0], acc[i][q*4+1],
                                       acc[i][q*4+2], acc[i][q*4+3]);
                *(float4*)&C[(size_t)grow * 128 + cbase + q * 4] = v;
            }
        }
    }
}

// ---------------- scatter: e_raw[edge] += y[node]  (one wave per nz) --------
__global__ __launch_bounds__(256) void scatter_to_edges(
    const float* __restrict__ y, const int* __restrict__ nidx,
    const int* __restrict__ eidx, float* __restrict__ e, int nnz)
{
    int gw = (blockIdx.x * 256 + threadIdx.x) >> 6;
    if (gw >= nnz) return;
    int lane = threadIdx.x & 63;
    int n  = nidx[gw];
    int ed = eidx[gw];
    float2 v = *(const float2*)&y[(size_t)n * 128 + lane * 2];
    float* dst = &e[(size_t)ed * 128 + lane * 2];
    atomAddF(dst + 0, v.x);
    atomAddF(dst + 1, v.y);
}

// ---------------- scatter: z_raw[node] += Binv[edge]*e_raw[edge] ------------
__global__ __launch_bounds__(256) void scatter_to_nodes(
    const float* __restrict__ e, const float* __restrict__ binv,
    const int* __restrict__ nidx, const int* __restrict__ eidx,
    float* __restrict__ z, int nnz)
{
    int gw = (blockIdx.x * 256 + threadIdx.x) >> 6;
    if (gw >= nnz) return;
    int lane = threadIdx.x & 63;
    int n  = nidx[gw];
    int ed = eidx[gw];
    float bi = binv[ed];
    float2 v = *(const float2*)&e[(size_t)ed * 128 + lane * 2];
    float* dst = &z[(size_t)n * 128 + lane * 2];
    atomAddF(dst + 0, v.x * bi);
    atomAddF(dst + 1, v.y * bi);
}

// ---------------- BN stats over v = z*Dinv[row] + bias[col] -----------------
__global__ __launch_bounds__(256) void bn_stats(
    const float* __restrict__ z, const float* __restrict__ dinv,
    const float* __restrict__ bias, float* __restrict__ gsum,
    float* __restrict__ gsq, int M)
{
    __shared__ float ssum[256], ssq[256];
    int col  = threadIdx.x & 127;
    int half = threadIdx.x >> 7;
    int base = blockIdx.x * 128;
    float s = 0.0f, q = 0.0f;
    for (int r = half; r < 128; r += 2) {
        int row = base + r;
        if (row < M) {
            float v = z[(size_t)row * 128 + col] * dinv[row] + bias[col];
            s += v; q += v * v;
        }
    }
    ssum[threadIdx.x] = s; ssq[threadIdx.x] = q;
    __syncthreads();
    if (half == 0) {
        atomAddF(&gsum[col], ssum[col] + ssum[col + 128]);
        atomAddF(&gsq[col],  ssq[col]  + ssq[col + 128]);
    }
}

__global__ void bn_finalize(
    const float* __restrict__ gsum, const float* __restrict__ gsq,
    const float* __restrict__ g, const float* __restrict__ bt,
    float* __restrict__ scale, float* __restrict__ shift, float invM)
{
    int c = threadIdx.x;  // 128 threads
    float mean = gsum[c] * invM;
    float var  = gsq[c] * invM - mean * mean;
    if (var < 0.0f) var = 0.0f;
    float sc = g[c] * rsqrtf(var + 1e-5f);
    scale[c] = sc;
    shift[c] = bt[c] - mean * sc;
}

// ---------------- BN apply + ReLU: h = relu((z*Dinv+b)*scale+shift) ---------
__global__ __launch_bounds__(256) void bn_apply(
    const float* __restrict__ z, const float* __restrict__ dinv,
    const float* __restrict__ bias, const float* __restrict__ scale,
    const float* __restrict__ shift, float* __restrict__ h, int M)
{
    int t = blockIdx.x * 256 + threadIdx.x;
    int row = t >> 5;
    if (row >= M) return;
    int c4 = (t & 31) * 4;
    float di = dinv[row];
    float4 zv = *(const float4*)&z[(size_t)row * 128 + c4];
    float4 bv = *(const float4*)&bias[c4];
    float4 sc = *(const float4*)&scale[c4];
    float4 sh = *(const float4*)&shift[c4];
    float4 o;
    o.x = fmaxf((zv.x * di + bv.x) * sc.x + sh.x, 0.0f);
    o.y = fmaxf((zv.y * di + bv.y) * sc.y + sh.y, 0.0f);
    o.z = fmaxf((zv.z * di + bv.z) * sc.z + sh.z, 0.0f);
    o.w = fmaxf((zv.w * di + bv.w) * sc.w + sh.w, 0.0f);
    *(float4*)&h[(size_t)row * 128 + c4] = o;
}

// ---------------- fused classifier: out = relu(h@Wc1+bc1)@Wc2+bc2 -----------
__global__ __launch_bounds__(256) void classifier_kernel(
    const float* __restrict__ h, const float* __restrict__ Wc1,
    const float* __restrict__ bc1, const float* __restrict__ Wc2,
    const float* __restrict__ bc2, float* __restrict__ out, int M)
{
    __shared__ float W1s[128 * 64];
    __shared__ float W2s[64 * 10];
    __shared__ float b1s[64];
    __shared__ float b2s[16];
    __shared__ float hs[4][128];
    __shared__ float hids[4][64];
    int tid = threadIdx.x;
    for (int i = tid; i < 128 * 64; i += 256) W1s[i] = Wc1[i];
    for (int i = tid; i < 64 * 10; i += 256)  W2s[i] = Wc2[i];
    if (tid < 64) b1s[tid] = bc1[tid];
    if (tid < 10) b2s[tid] = bc2[tid];

    int w = tid >> 6, lane = tid & 63;
    int row = blockIdx.x * 4 + w;     // M divisible by 4: no guard
    float2 hv = *(const float2*)&h[(size_t)row * 128 + lane * 2];
    hs[w][lane * 2 + 0] = hv.x;
    hs[w][lane * 2 + 1] = hv.y;
    __syncthreads();

    float acc = b1s[lane];
#pragma unroll 8
    for (int k = 0; k < 128; k++) acc += hs[w][k] * W1s[k * 64 + lane];
    hids[w][lane] = fmaxf(acc, 0.0f);
    __syncthreads();

    if (lane < 10) {
        float o = b2s[lane];
#pragma unroll 8
        for (int k = 0; k < 64; k++) o += hids[w][k] * W2s[k * 10 + lane];
        out[(size_t)row * 10 + lane] = o;
    }
}

// ---------------- launch ----------------------------------------------------
extern "C" void kernel_launch(void* const* d_in, const int* in_sizes, int n_in,
                              void* d_out, int out_size, void* d_ws, size_t ws_size,
                              hipStream_t stream)
{
    const int M   = N_NODES;
    const int nnz = NNZ_C;

    const float* x   = (const float*)d_in[0];
    const int*  nidx = (const int*)d_in[1];
    const int*  eidx = nidx + nnz;
    const float* W1  = (const float*)d_in[2];
    const float* b1  = (const float*)d_in[3];
    const float* W2  = (const float*)d_in[4];
    const float* b2  = (const float*)d_in[5];
    const float* W3  = (const float*)d_in[6];
    const float* b3  = (const float*)d_in[7];
    const float* g1  = (const float*)d_in[8];
    const float* bt1 = (const float*)d_in[9];
    const float* g2  = (const float*)d_in[10];
    const float* bt2 = (const float*)d_in[11];
    const float* g3  = (const float*)d_in[12];
    const float* bt3 = (const float*)d_in[13];
    const float* Wc1 = (const float*)d_in[14];
    const float* bc1 = (const float*)d_in[15];
    const float* Wc2 = (const float*)d_in[16];
    const float* bc2 = (const float*)d_in[17];
    float* out = (float*)d_out;

    // workspace carve-up
    const size_t SZ = (size_t)M * 128 * sizeof(float);   // 51.2 MB
    char* ws = (char*)d_ws;
    float* A    = (float*)(ws);                 // y / z_raw (reused)
    float* B    = (float*)(ws + SZ);            // e_raw
    float* H    = (float*)(ws + 2 * SZ);        // post-BN activations
    char*  sm   = ws + 3 * SZ;
    int*   cntD = (int*)(sm);                   // 400 KB
    int*   cntB = (int*)(sm + 400000);
    float* Dinv = (float*)(sm + 800000);
    float* Binv = (float*)(sm + 1200000);
    float* gsum = (float*)(sm + 1600000);
    float* gsq  = (float*)(sm + 1600512);
    float* bscale = (float*)(sm + 1601024);
    float* bshift = (float*)(sm + 1601536);

    const int scatter_blocks = (nnz * 64) / 256;        // 150000
    const int gemm_blocks    = (M + 127) / 128;         // 782
    const int stats_blocks   = (M + 127) / 128;         // 782
    const int apply_blocks   = (M * 32) / 256;          // 12500

    // degrees (once)
    hipMemsetAsync(cntD, 0, 800000, stream);
    degrees_kernel<<<(nnz + 255) / 256, 256, 0, stream>>>(nidx, eidx, cntD, cntB, nnz);
    make_inv_kernel<<<(M + 255) / 256, 256, 0, stream>>>(cntD, cntB, Dinv, Binv, M);

    const float* Win[3]  = { W1, W2, W3 };
    const float* bin[3]  = { b1, b2, b3 };
    const float* gin[3]  = { g1, g2, g3 };
    const float* btin[3] = { bt1, bt2, bt3 };

    for (int L = 0; L < 3; L++) {
        // GEMM: A = prev @ W_L
        if (L == 0)
            gemm_f32<256><<<gemm_blocks, 256, 0, stream>>>(x, Win[L], A, M);
        else
            gemm_f32<128><<<gemm_blocks, 256, 0, stream>>>(H, Win[L], A, M);
        // edge aggregation
        hipMemsetAsync(B, 0, SZ, stream);
        scatter_to_edges<<<scatter_blocks, 256, 0, stream>>>(A, nidx, eidx, B, nnz);
        // node aggregation (Binv folded in)
        hipMemsetAsync(A, 0, SZ, stream);
        scatter_to_nodes<<<scatter_blocks, 256, 0, stream>>>(B, Binv, nidx, eidx, A, nnz);
        // BN stats + apply (Dinv and conv-bias folded in)
        hipMemsetAsync(gsum, 0, 1024, stream);
        bn_stats<<<stats_blocks, 256, 0, stream>>>(A, Dinv, bin[L], gsum, gsq, M);
        bn_finalize<<<1, 128, 0, stream>>>(gsum, gsq, gin[L], btin[L], bscale, bshift, 1.0f / (float)M);
        bn_apply<<<apply_blocks, 256, 0, stream>>>(A, Dinv, bin[L], bscale, bshift, H, M);
    }

    classifier_kernel<<<M / 4, 256, 0, stream>>>(H, Wc1, bc1, Wc2, bc2, out, M);
}

// Round 2
// 1687.365 us; speedup vs baseline: 2.4540x; 2.4540x over previous
//
#include <hip/hip_runtime.h>

#define N_NODES 100000
#define N_EDGES 100000
#define NNZ_C   600000

__device__ __forceinline__ void atomAddF(float* p, float v) {
    unsafeAtomicAdd(p, v);   // hardware global_atomic_add_f32 on gfx950
}

// ---------------- degree histograms -----------------------------------------
__global__ __launch_bounds__(256) void degrees_kernel(
    const int* __restrict__ nidx, const int* __restrict__ eidx,
    int* __restrict__ cd, int* __restrict__ cb, int nnz)
{
    int i = blockIdx.x * 256 + threadIdx.x;
    if (i < nnz) {
        atomicAdd(&cd[nidx[i]], 1);
        atomicAdd(&cb[eidx[i]], 1);
    }
}

__global__ __launch_bounds__(256) void make_inv_kernel(
    const int* __restrict__ cd, const int* __restrict__ cb,
    float* __restrict__ dinv, float* __restrict__ binv, int n)
{
    int i = blockIdx.x * 256 + threadIdx.x;
    if (i < n) {
        int d = cd[i], b = cb[i];
        dinv[i] = d > 0 ? 1.0f / (float)d : 0.0f;
        binv[i] = b > 0 ? 1.0f / (float)b : 0.0f;
    }
}

// ---------------- CSR build: block scan pipeline -----------------------------
__global__ __launch_bounds__(256) void block_partials(
    const int* __restrict__ cnt, int* __restrict__ part, int n)
{
    __shared__ int s[256];
    int i = blockIdx.x * 256 + threadIdx.x;
    s[threadIdx.x] = (i < n) ? cnt[i] : 0;
    __syncthreads();
#pragma unroll
    for (int off = 128; off > 0; off >>= 1) {
        if (threadIdx.x < off) s[threadIdx.x] += s[threadIdx.x + off];
        __syncthreads();
    }
    if (threadIdx.x == 0) part[blockIdx.x] = s[0];
}

__global__ __launch_bounds__(512) void scan_partials(int* __restrict__ part, int nb)
{
    __shared__ int s[512];
    int t = threadIdx.x;
    s[t] = (t < nb) ? part[t] : 0;
    __syncthreads();
#pragma unroll
    for (int off = 1; off < 512; off <<= 1) {
        int v = (t >= off) ? s[t - off] : 0;
        __syncthreads();
        s[t] += v;
        __syncthreads();
    }
    if (t < nb) part[t] = s[t];   // inclusive block sums
}

__global__ __launch_bounds__(256) void scan_final(
    const int* __restrict__ cnt, const int* __restrict__ part,
    int* __restrict__ rowptr, int* __restrict__ cursor, int n)
{
    __shared__ int s[256];
    int i = blockIdx.x * 256 + threadIdx.x;
    int v = (i < n) ? cnt[i] : 0;
    s[threadIdx.x] = v;
    __syncthreads();
#pragma unroll
    for (int off = 1; off < 256; off <<= 1) {
        int t = (threadIdx.x >= off) ? s[threadIdx.x - off] : 0;
        __syncthreads();
        s[threadIdx.x] += t;
        __syncthreads();
    }
    int base = (blockIdx.x > 0) ? part[blockIdx.x - 1] : 0;
    if (i < n) {
        int excl = base + s[threadIdx.x] - v;
        rowptr[i] = excl;
        cursor[i] = excl;
        if (i == n - 1) rowptr[n] = base + s[threadIdx.x];
    }
}

__global__ __launch_bounds__(256) void fill_csr(
    const int* __restrict__ nidx, const int* __restrict__ eidx,
    int* __restrict__ curB, int* __restrict__ curD,
    int* __restrict__ colB, int* __restrict__ colD, int nnz)
{
    int i = blockIdx.x * 256 + threadIdx.x;
    if (i < nnz) {
        int n = nidx[i], e = eidx[i];
        colB[atomicAdd(&curB[e], 1)] = n;   // edge -> member nodes
        colD[atomicAdd(&curD[n], 1)] = e;   // node -> incident edges
    }
}

// ---------------- fp32 GEMM: C[M,128] = A[M,KDIM] @ W[KDIM,128] -------------
template<int KDIM>
__global__ __launch_bounds__(256) void gemm_f32(
    const float* __restrict__ A, const float* __restrict__ W,
    float* __restrict__ C, int M)
{
    __shared__ float As[128][33];
    __shared__ float Ws[32][128];
    const int tid  = threadIdx.x;
    const int row0 = blockIdx.x * 128;
    const int cg   = tid & 7;
    const int rg   = tid >> 3;
    const int rbase = rg * 4;
    const int cbase = cg * 16;

    float acc[4][16];
#pragma unroll
    for (int i = 0; i < 4; i++)
#pragma unroll
        for (int j = 0; j < 16; j++) acc[i][j] = 0.0f;

    for (int k0 = 0; k0 < KDIM; k0 += 32) {
        __syncthreads();
#pragma unroll
        for (int i = 0; i < 16; i++) {
            int e = tid + i * 256;
            int r = e >> 5, kk = e & 31;
            int grow = row0 + r;
            As[r][kk] = (grow < M) ? A[(size_t)grow * KDIM + k0 + kk] : 0.0f;
        }
#pragma unroll
        for (int i = 0; i < 16; i++) {
            int e = tid + i * 256;
            int kk = e >> 7, c = e & 127;
            Ws[kk][c] = W[(size_t)(k0 + kk) * 128 + c];
        }
        __syncthreads();
#pragma unroll
        for (int kk = 0; kk < 32; kk++) {
            float a0 = As[rbase + 0][kk];
            float a1 = As[rbase + 1][kk];
            float a2 = As[rbase + 2][kk];
            float a3 = As[rbase + 3][kk];
#pragma unroll
            for (int q = 0; q < 4; q++) {
                const float4 w = *(const float4*)&Ws[kk][cbase + q * 4];
                acc[0][q*4+0] += a0 * w.x; acc[0][q*4+1] += a0 * w.y;
                acc[0][q*4+2] += a0 * w.z; acc[0][q*4+3] += a0 * w.w;
                acc[1][q*4+0] += a1 * w.x; acc[1][q*4+1] += a1 * w.y;
                acc[1][q*4+2] += a1 * w.z; acc[1][q*4+3] += a1 * w.w;
                acc[2][q*4+0] += a2 * w.x; acc[2][q*4+1] += a2 * w.y;
                acc[2][q*4+2] += a2 * w.z; acc[2][q*4+3] += a2 * w.w;
                acc[3][q*4+0] += a3 * w.x; acc[3][q*4+1] += a3 * w.y;
                acc[3][q*4+2] += a3 * w.z; acc[3][q*4+3] += a3 * w.w;
            }
        }
    }
#pragma unroll
    for (int i = 0; i < 4; i++) {
        int grow = row0 + rbase + i;
        if (grow < M) {
#pragma unroll
            for (int q = 0; q < 4; q++) {
                float4 v = make_float4(acc[i][q*4+0], acc[i][q*4+1],
                                       acc[i][q*4+2], acc[i][q*4+3]);
                *(float4*)&C[(size_t)grow * 128 + cbase + q * 4] = v;
            }
        }
    }
}

// ---------------- gather: e[edge] = Binv[edge] * sum_{n in edge} y[n] -------
__global__ __launch_bounds__(256) void gather_rows(
    const float* __restrict__ src, const int* __restrict__ rowptr,
    const int* __restrict__ col, const float* __restrict__ wgt,
    float* __restrict__ dst, int nrows)
{
    int r = blockIdx.x * 4 + (threadIdx.x >> 6);
    if (r >= nrows) return;
    int lane = threadIdx.x & 63;
    int p0 = rowptr[r], p1 = rowptr[r + 1];
    float ax = 0.0f, ay = 0.0f;
    for (int p = p0; p < p1; p++) {
        int s = col[p];
        float2 v = *(const float2*)&src[(size_t)s * 128 + lane * 2];
        ax += v.x; ay += v.y;
    }
    float w = wgt[r];
    *(float2*)&dst[(size_t)r * 128 + lane * 2] = make_float2(ax * w, ay * w);
}

// ---------------- BN stats over v = z[row][col] + bias[col] -----------------
__global__ __launch_bounds__(256) void bn_stats(
    const float* __restrict__ z, const float* __restrict__ bias,
    float* __restrict__ gsum, float* __restrict__ gsq, int M)
{
    __shared__ float ssum[256], ssq[256];
    int col  = threadIdx.x & 127;
    int half = threadIdx.x >> 7;
    int base = blockIdx.x * 128;
    float bc = bias[col];
    float s = 0.0f, q = 0.0f;
    for (int r = half; r < 128; r += 2) {
        int row = base + r;
        if (row < M) {
            float v = z[(size_t)row * 128 + col] + bc;
            s += v; q += v * v;
        }
    }
    ssum[threadIdx.x] = s; ssq[threadIdx.x] = q;
    __syncthreads();
    if (half == 0) {
        atomAddF(&gsum[col], ssum[col] + ssum[col + 128]);
        atomAddF(&gsq[col],  ssq[col]  + ssq[col + 128]);
    }
}

__global__ void bn_finalize(
    const float* __restrict__ gsum, const float* __restrict__ gsq,
    const float* __restrict__ g, const float* __restrict__ bt,
    float* __restrict__ scale, float* __restrict__ shift, float invM)
{
    int c = threadIdx.x;  // 128 threads
    float mean = gsum[c] * invM;
    float var  = gsq[c] * invM - mean * mean;
    if (var < 0.0f) var = 0.0f;
    float sc = g[c] * rsqrtf(var + 1e-5f);
    scale[c] = sc;
    shift[c] = bt[c] - mean * sc;
}

// ---------------- BN apply + ReLU: h = relu((z+b)*scale+shift) --------------
__global__ __launch_bounds__(256) void bn_apply(
    const float* __restrict__ z, const float* __restrict__ bias,
    const float* __restrict__ scale, const float* __restrict__ shift,
    float* __restrict__ h, int M)
{
    int t = blockIdx.x * 256 + threadIdx.x;
    int row = t >> 5;
    if (row >= M) return;
    int c4 = (t & 31) * 4;
    float4 zv = *(const float4*)&z[(size_t)row * 128 + c4];
    float4 bv = *(const float4*)&bias[c4];
    float4 sc = *(const float4*)&scale[c4];
    float4 sh = *(const float4*)&shift[c4];
    float4 o;
    o.x = fmaxf((zv.x + bv.x) * sc.x + sh.x, 0.0f);
    o.y = fmaxf((zv.y + bv.y) * sc.y + sh.y, 0.0f);
    o.z = fmaxf((zv.z + bv.z) * sc.z + sh.z, 0.0f);
    o.w = fmaxf((zv.w + bv.w) * sc.w + sh.w, 0.0f);
    *(float4*)&h[(size_t)row * 128 + c4] = o;
}

// ---------------- fused classifier: out = relu(h@Wc1+bc1)@Wc2+bc2 -----------
__global__ __launch_bounds__(256) void classifier_kernel(
    const float* __restrict__ h, const float* __restrict__ Wc1,
    const float* __restrict__ bc1, const float* __restrict__ Wc2,
    const float* __restrict__ bc2, float* __restrict__ out, int M)
{
    __shared__ float W1s[128 * 64];
    __shared__ float W2s[64 * 10];
    __shared__ float b1s[64];
    __shared__ float b2s[16];
    __shared__ float hs[4][128];
    __shared__ float hids[4][64];
    int tid = threadIdx.x;
    for (int i = tid; i < 128 * 64; i += 256) W1s[i] = Wc1[i];
    for (int i = tid; i < 64 * 10; i += 256)  W2s[i] = Wc2[i];
    if (tid < 64) b1s[tid] = bc1[tid];
    if (tid < 10) b2s[tid] = bc2[tid];

    int w = tid >> 6, lane = tid & 63;
    int row = blockIdx.x * 4 + w;     // M divisible by 4: no guard
    float2 hv = *(const float2*)&h[(size_t)row * 128 + lane * 2];
    hs[w][lane * 2 + 0] = hv.x;
    hs[w][lane * 2 + 1] = hv.y;
    __syncthreads();

    float acc = b1s[lane];
#pragma unroll 8
    for (int k = 0; k < 128; k++) acc += hs[w][k] * W1s[k * 64 + lane];
    hids[w][lane] = fmaxf(acc, 0.0f);
    __syncthreads();

    if (lane < 10) {
        float o = b2s[lane];
#pragma unroll 8
        for (int k = 0; k < 64; k++) o += hids[w][k] * W2s[k * 10 + lane];
        out[(size_t)row * 10 + lane] = o;
    }
}

// ---------------- launch ----------------------------------------------------
extern "C" void kernel_launch(void* const* d_in, const int* in_sizes, int n_in,
                              void* d_out, int out_size, void* d_ws, size_t ws_size,
                              hipStream_t stream)
{
    const int M   = N_NODES;
    const int NE  = N_EDGES;
    const int nnz = NNZ_C;

    const float* x   = (const float*)d_in[0];
    const int*  nidx = (const int*)d_in[1];
    const int*  eidx = nidx + nnz;
    const float* W1  = (const float*)d_in[2];
    const float* b1  = (const float*)d_in[3];
    const float* W2  = (const float*)d_in[4];
    const float* b2  = (const float*)d_in[5];
    const float* W3  = (const float*)d_in[6];
    const float* b3  = (const float*)d_in[7];
    const float* g1  = (const float*)d_in[8];
    const float* bt1 = (const float*)d_in[9];
    const float* g2  = (const float*)d_in[10];
    const float* bt2 = (const float*)d_in[11];
    const float* g3  = (const float*)d_in[12];
    const float* bt3 = (const float*)d_in[13];
    const float* Wc1 = (const float*)d_in[14];
    const float* bc1 = (const float*)d_in[15];
    const float* Wc2 = (const float*)d_in[16];
    const float* bc2 = (const float*)d_in[17];
    float* out = (float*)d_out;

    // ---- workspace carve-up ----
    const size_t SZ = (size_t)M * 128 * sizeof(float);   // 51.2 MB
    char* ws = (char*)d_ws;
    float* A = (float*)(ws);                 // y / z (reused)
    float* B = (float*)(ws + SZ);            // e (per-edge features)
    float* H = (float*)(ws + 2 * SZ);        // post-BN activations
    int* ib = (int*)(ws + 3 * SZ);
    int*   cntD    = ib;                     // node degree counts   [100000]
    int*   cntB    = ib + 100000;            // edge size counts     [100000]
    int*   rowptrD = ib + 200000;            // node CSR rowptr      [100001]
    int*   rowptrB = ib + 300002;            // edge CSR rowptr      [100001]
    int*   curD    = ib + 400004;            // fill cursors         [100000]
    int*   curB    = ib + 500004;
    int*   colD    = ib + 600004;            // node -> edges        [600000]
    int*   colB    = ib + 1200004;           // edge -> nodes        [600000]
    int*   partD   = ib + 1800004;           // scan partials        [391]
    int*   partB   = ib + 1800404;
    float* fb = (float*)(ib + 1800804);
    float* Dinv   = fb;                      // [100000]
    float* Binv   = fb + 100000;
    float* gsum   = fb + 200000;             // [128]
    float* gsq    = fb + 200128;
    float* bscale = fb + 200256;
    float* bshift = fb + 200384;

    const int nb_scan      = (M + 255) / 256;            // 391 (M == NE)
    const int gemm_blocks  = (M + 127) / 128;
    const int stats_blocks = (M + 127) / 128;
    const int apply_blocks = (M * 32) / 256;
    const int gather_blkN  = (M + 3) / 4;
    const int gather_blkE  = (NE + 3) / 4;

    // ---- CSR build (per call; ws is re-poisoned before every launch) ----
    hipMemsetAsync(cntD, 0, 800000, stream);   // cntD + cntB
    degrees_kernel<<<(nnz + 255) / 256, 256, 0, stream>>>(nidx, eidx, cntD, cntB, nnz);
    make_inv_kernel<<<(M + 255) / 256, 256, 0, stream>>>(cntD, cntB, Dinv, Binv, M);
    block_partials<<<nb_scan, 256, 0, stream>>>(cntD, partD, M);
    block_partials<<<nb_scan, 256, 0, stream>>>(cntB, partB, NE);
    scan_partials<<<1, 512, 0, stream>>>(partD, nb_scan);
    scan_partials<<<1, 512, 0, stream>>>(partB, nb_scan);
    scan_final<<<nb_scan, 256, 0, stream>>>(cntD, partD, rowptrD, curD, M);
    scan_final<<<nb_scan, 256, 0, stream>>>(cntB, partB, rowptrB, curB, NE);
    fill_csr<<<(nnz + 255) / 256, 256, 0, stream>>>(nidx, eidx, curB, curD, colB, colD, nnz);

    const float* Win[3]  = { W1, W2, W3 };
    const float* bin[3]  = { b1, b2, b3 };
    const float* gin[3]  = { g1, g2, g3 };
    const float* btin[3] = { bt1, bt2, bt3 };

    for (int L = 0; L < 3; L++) {
        // GEMM: A = prev @ W_L
        if (L == 0)
            gemm_f32<256><<<gemm_blocks, 256, 0, stream>>>(x, Win[L], A, M);
        else
            gemm_f32<128><<<gemm_blocks, 256, 0, stream>>>(H, Win[L], A, M);
        // edge aggregation: B[e] = Binv[e] * sum y[members]
        gather_rows<<<gather_blkE, 256, 0, stream>>>(A, rowptrB, colB, Binv, B, NE);
        // node aggregation: A[n] = Dinv[n] * sum B[incident]
        gather_rows<<<gather_blkN, 256, 0, stream>>>(B, rowptrD, colD, Dinv, A, M);
        // BN stats + apply (conv-bias folded in)
        hipMemsetAsync(gsum, 0, 1024, stream);
        bn_stats<<<stats_blocks, 256, 0, stream>>>(A, bin[L], gsum, gsq, M);
        bn_finalize<<<1, 128, 0, stream>>>(gsum, gsq, gin[L], btin[L], bscale, bshift, 1.0f / (float)M);
        bn_apply<<<apply_blocks, 256, 0, stream>>>(A, bin[L], bscale, bshift, H, M);
    }

    classifier_kernel<<<M / 4, 256, 0, stream>>>(H, Wc1, bc1, Wc2, bc2, out, M);
}

// Round 3
// 1179.245 us; speedup vs baseline: 3.5114x; 1.4309x over previous
//
#include <hip/hip_runtime.h>

#define N_NODES 100000
#define N_EDGES 100000
#define NNZ_C   600000

typedef unsigned short u16;
typedef __attribute__((ext_vector_type(8))) short short8;
typedef __attribute__((ext_vector_type(4))) float float4v;

__device__ __forceinline__ void atomAddF(float* p, float v) {
    unsafeAtomicAdd(p, v);   // hardware global_atomic_add_f32 on gfx950
}

__device__ __forceinline__ u16 f2bf(float f) {     // RNE fp32 -> bf16
    union { float f; unsigned int i; } x; x.f = f;
    unsigned int r = x.i + 0x7FFFu + ((x.i >> 16) & 1u);
    return (u16)(r >> 16);
}
__device__ __forceinline__ float bf2f(u16 u) {
    union { float f; unsigned int i; } x; x.i = ((unsigned int)u) << 16; return x.f;
}

// ---------------- fp32 -> bf16 conversion -----------------------------------
__global__ __launch_bounds__(256) void f32_to_bf16_k(
    const float* __restrict__ src, u16* __restrict__ dst, int n4)
{
    int i = blockIdx.x * 256 + threadIdx.x;
    if (i < n4) {
        float4 v = *(const float4*)(src + (size_t)i * 4);
        ushort4 o;
        o.x = f2bf(v.x); o.y = f2bf(v.y); o.z = f2bf(v.z); o.w = f2bf(v.w);
        *(ushort4*)(dst + (size_t)i * 4) = o;
    }
}

// ---------------- degree histograms -----------------------------------------
__global__ __launch_bounds__(256) void degrees_kernel(
    const int* __restrict__ nidx, const int* __restrict__ eidx,
    int* __restrict__ cd, int* __restrict__ cb, int nnz)
{
    int i = blockIdx.x * 256 + threadIdx.x;
    if (i < nnz) {
        atomicAdd(&cd[nidx[i]], 1);
        atomicAdd(&cb[eidx[i]], 1);
    }
}

__global__ __launch_bounds__(256) void make_inv_kernel(
    const int* __restrict__ cd, const int* __restrict__ cb,
    float* __restrict__ dinv, float* __restrict__ binv, int n)
{
    int i = blockIdx.x * 256 + threadIdx.x;
    if (i < n) {
        int d = cd[i], b = cb[i];
        dinv[i] = d > 0 ? 1.0f / (float)d : 0.0f;
        binv[i] = b > 0 ? 1.0f / (float)b : 0.0f;
    }
}

// ---------------- CSR build: block scan pipeline -----------------------------
__global__ __launch_bounds__(256) void block_partials(
    const int* __restrict__ cnt, int* __restrict__ part, int n)
{
    __shared__ int s[256];
    int i = blockIdx.x * 256 + threadIdx.x;
    s[threadIdx.x] = (i < n) ? cnt[i] : 0;
    __syncthreads();
#pragma unroll
    for (int off = 128; off > 0; off >>= 1) {
        if (threadIdx.x < off) s[threadIdx.x] += s[threadIdx.x + off];
        __syncthreads();
    }
    if (threadIdx.x == 0) part[blockIdx.x] = s[0];
}

__global__ __launch_bounds__(512) void scan_partials(int* __restrict__ part, int nb)
{
    __shared__ int s[512];
    int t = threadIdx.x;
    s[t] = (t < nb) ? part[t] : 0;
    __syncthreads();
#pragma unroll
    for (int off = 1; off < 512; off <<= 1) {
        int v = (t >= off) ? s[t - off] : 0;
        __syncthreads();
        s[t] += v;
        __syncthreads();
    }
    if (t < nb) part[t] = s[t];   // inclusive block sums
}

__global__ __launch_bounds__(256) void scan_final(
    const int* __restrict__ cnt, const int* __restrict__ part,
    int* __restrict__ rowptr, int* __restrict__ cursor, int n)
{
    __shared__ int s[256];
    int i = blockIdx.x * 256 + threadIdx.x;
    int v = (i < n) ? cnt[i] : 0;
    s[threadIdx.x] = v;
    __syncthreads();
#pragma unroll
    for (int off = 1; off < 256; off <<= 1) {
        int t = (threadIdx.x >= off) ? s[threadIdx.x - off] : 0;
        __syncthreads();
        s[threadIdx.x] += t;
        __syncthreads();
    }
    int base = (blockIdx.x > 0) ? part[blockIdx.x - 1] : 0;
    if (i < n) {
        int excl = base + s[threadIdx.x] - v;
        rowptr[i] = excl;
        cursor[i] = excl;
        if (i == n - 1) rowptr[n] = base + s[threadIdx.x];
    }
}

__global__ __launch_bounds__(256) void fill_csr(
    const int* __restrict__ nidx, const int* __restrict__ eidx,
    int* __restrict__ curB, int* __restrict__ curD,
    int* __restrict__ colB, int* __restrict__ colD, int nnz)
{
    int i = blockIdx.x * 256 + threadIdx.x;
    if (i < nnz) {
        int n = nidx[i], e = eidx[i];
        colB[atomicAdd(&curB[e], 1)] = n;
        colD[atomicAdd(&curD[n], 1)] = e;
    }
}

// ---------------- bf16 MFMA GEMM: C[M,128] = A[M,K](bf16) @ W[K,128](bf16) --
// Block = 256 thr (4 waves). Tile = 128 rows. Wave handles 32 rows x 128 cols
// = 2x8 grid of 16x16x32 MFMAs. W transposed+rotation-swizzled in LDS (read
// once per block); A-fragments loaded straight from global as 16-B chunks
// (frag layout A[m=lane&15][k=quad*8+j] == contiguous dwordx4). No barriers
// in the K-loop.
template<int KDIM>
__global__ __launch_bounds__(256) void gemm_mfma(
    const u16* __restrict__ A, const u16* __restrict__ Wb,
    float* __restrict__ C, int M, int ntiles)
{
    constexpr int BMASK = KDIM / 8 - 1;
    __shared__ u16 Wt[128 * KDIM];          // Wt[n][k] rotated: 64/32 KB
    const int tid = threadIdx.x;

    // stage Wt[n][rot(k,n)] = Wb[k][n]; coalesced uint2 global reads
    for (int i = tid * 4; i < 128 * KDIM; i += 1024) {
        int k = i >> 7, n0 = i & 127;
        uint2 v = *(const uint2*)(Wb + i);
        int kb = k >> 3, kin = k & 7;
        Wt[(n0 + 0) * KDIM + (((kb + n0 + 0) & BMASK) << 3) + kin] = (u16)(v.x & 0xFFFF);
        Wt[(n0 + 1) * KDIM + (((kb + n0 + 1) & BMASK) << 3) + kin] = (u16)(v.x >> 16);
        Wt[(n0 + 2) * KDIM + (((kb + n0 + 2) & BMASK) << 3) + kin] = (u16)(v.y & 0xFFFF);
        Wt[(n0 + 3) * KDIM + (((kb + n0 + 3) & BMASK) << 3) + kin] = (u16)(v.y >> 16);
    }
    __syncthreads();

    const int wave = tid >> 6, lane = tid & 63;
    const int l16 = lane & 15, quad = lane >> 4;

    for (int tile = blockIdx.x; tile < ntiles; tile += gridDim.x) {
        const int rowt = tile * 128 + wave * 32;
        const int r0 = rowt + l16, r1 = rowt + 16 + l16;
        const bool v0 = r0 < M, v1 = r1 < M;
        const u16* a0p = A + (size_t)(v0 ? r0 : 0) * KDIM + quad * 8;
        const u16* a1p = A + (size_t)(v1 ? r1 : 0) * KDIM + quad * 8;

        float4v acc[2][8];
#pragma unroll
        for (int g = 0; g < 2; g++)
#pragma unroll
            for (int c = 0; c < 8; c++) acc[g][c] = (float4v)0.0f;

        for (int k0 = 0; k0 < KDIM; k0 += 32) {
            short8 af0 = *(const short8*)(a0p + k0);
            short8 af1 = *(const short8*)(a1p + k0);
            if (!v0) af0 = (short8)(short)0;
            if (!v1) af1 = (short8)(short)0;
            const int kb = (k0 >> 3) + quad;
#pragma unroll
            for (int c = 0; c < 8; c++) {
                const int n = c * 16 + l16;
                short8 bf = *(const short8*)&Wt[n * KDIM + (((kb + n) & BMASK) << 3)];
                acc[0][c] = __builtin_amdgcn_mfma_f32_16x16x32_bf16(af0, bf, acc[0][c], 0, 0, 0);
                acc[1][c] = __builtin_amdgcn_mfma_f32_16x16x32_bf16(af1, bf, acc[1][c], 0, 0, 0);
            }
        }
        // C/D layout: col = lane&15, row = quad*4 + reg
#pragma unroll
        for (int g = 0; g < 2; g++) {
#pragma unroll
            for (int r = 0; r < 4; r++) {
                int row = rowt + g * 16 + quad * 4 + r;
                if (row < M) {
                    float* crow = C + (size_t)row * 128 + l16;
#pragma unroll
                    for (int c = 0; c < 8; c++) crow[c * 16] = acc[g][c][r];
                }
            }
        }
    }
}

// ---------------- gather: dst[r] = wgt[r] * sum_{s in row r} src[s] ---------
__global__ __launch_bounds__(256) void gather_rows(
    const float* __restrict__ src, const int* __restrict__ rowptr,
    const int* __restrict__ col, const float* __restrict__ wgt,
    float* __restrict__ dst, int nrows)
{
    int r = blockIdx.x * 4 + (threadIdx.x >> 6);
    if (r >= nrows) return;
    int lane = threadIdx.x & 63;
    int p0 = rowptr[r], p1 = rowptr[r + 1];
    float ax = 0.0f, ay = 0.0f;
    for (int p = p0; p < p1; p++) {
        int s = col[p];
        float2 v = *(const float2*)&src[(size_t)s * 128 + lane * 2];
        ax += v.x; ay += v.y;
    }
    float w = wgt[r];
    *(float2*)&dst[(size_t)r * 128 + lane * 2] = make_float2(ax * w, ay * w);
}

// ---------------- BN stats over v = z[row][col] + bias[col] -----------------
__global__ __launch_bounds__(256) void bn_stats(
    const float* __restrict__ z, const float* __restrict__ bias,
    float* __restrict__ gsum, float* __restrict__ gsq, int M)
{
    __shared__ float ssum[256], ssq[256];
    int col  = threadIdx.x & 127;
    int half = threadIdx.x >> 7;
    int base = blockIdx.x * 128;
    float bc = bias[col];
    float s = 0.0f, q = 0.0f;
    for (int r = half; r < 128; r += 2) {
        int row = base + r;
        if (row < M) {
            float v = z[(size_t)row * 128 + col] + bc;
            s += v; q += v * v;
        }
    }
    ssum[threadIdx.x] = s; ssq[threadIdx.x] = q;
    __syncthreads();
    if (half == 0) {
        atomAddF(&gsum[col], ssum[col] + ssum[col + 128]);
        atomAddF(&gsq[col],  ssq[col]  + ssq[col + 128]);
    }
}

__global__ void bn_finalize(
    const float* __restrict__ gsum, const float* __restrict__ gsq,
    const float* __restrict__ g, const float* __restrict__ bt,
    float* __restrict__ scale, float* __restrict__ shift, float invM)
{
    int c = threadIdx.x;  // 128 threads
    float mean = gsum[c] * invM;
    float var  = gsq[c] * invM - mean * mean;
    if (var < 0.0f) var = 0.0f;
    float sc = g[c] * rsqrtf(var + 1e-5f);
    scale[c] = sc;
    shift[c] = bt[c] - mean * sc;
}

// ---------------- BN apply + ReLU -> bf16 H ---------------------------------
__global__ __launch_bounds__(256) void bn_apply(
    const float* __restrict__ z, const float* __restrict__ bias,
    const float* __restrict__ scale, const float* __restrict__ shift,
    u16* __restrict__ h, int M)
{
    int t = blockIdx.x * 256 + threadIdx.x;
    int row = t >> 5;
    if (row >= M) return;
    int c4 = (t & 31) * 4;
    float4 zv = *(const float4*)&z[(size_t)row * 128 + c4];
    float4 bv = *(const float4*)&bias[c4];
    float4 sc = *(const float4*)&scale[c4];
    float4 sh = *(const float4*)&shift[c4];
    ushort4 o;
    o.x = f2bf(fmaxf((zv.x + bv.x) * sc.x + sh.x, 0.0f));
    o.y = f2bf(fmaxf((zv.y + bv.y) * sc.y + sh.y, 0.0f));
    o.z = f2bf(fmaxf((zv.z + bv.z) * sc.z + sh.z, 0.0f));
    o.w = f2bf(fmaxf((zv.w + bv.w) * sc.w + sh.w, 0.0f));
    *(ushort4*)&h[(size_t)row * 128 + c4] = o;
}

// ---------------- fused classifier: out = relu(h@Wc1+bc1)@Wc2+bc2 -----------
__global__ __launch_bounds__(256) void classifier_kernel(
    const u16* __restrict__ h, const float* __restrict__ Wc1,
    const float* __restrict__ bc1, const float* __restrict__ Wc2,
    const float* __restrict__ bc2, float* __restrict__ out, int M)
{
    __shared__ float W1s[128 * 64];
    __shared__ float W2s[64 * 10];
    __shared__ float b1s[64];
    __shared__ float b2s[16];
    __shared__ float hs[4][128];
    __shared__ float hids[4][64];
    int tid = threadIdx.x;
    for (int i = tid; i < 128 * 64; i += 256) W1s[i] = Wc1[i];
    for (int i = tid; i < 64 * 10; i += 256)  W2s[i] = Wc2[i];
    if (tid < 64) b1s[tid] = bc1[tid];
    if (tid < 10) b2s[tid] = bc2[tid];

    int w = tid >> 6, lane = tid & 63;
    int row = blockIdx.x * 4 + w;     // M divisible by 4: no guard
    unsigned int hv = *(const unsigned int*)&h[(size_t)row * 128 + lane * 2];
    hs[w][lane * 2 + 0] = bf2f((u16)(hv & 0xFFFF));
    hs[w][lane * 2 + 1] = bf2f((u16)(hv >> 16));
    __syncthreads();

    float acc = b1s[lane];
#pragma unroll 8
    for (int k = 0; k < 128; k++) acc += hs[w][k] * W1s[k * 64 + lane];
    hids[w][lane] = fmaxf(acc, 0.0f);
    __syncthreads();

    if (lane < 10) {
        float o = b2s[lane];
#pragma unroll 8
        for (int k = 0; k < 64; k++) o += hids[w][k] * W2s[k * 10 + lane];
        out[(size_t)row * 10 + lane] = o;
    }
}

// ---------------- launch ----------------------------------------------------
extern "C" void kernel_launch(void* const* d_in, const int* in_sizes, int n_in,
                              void* d_out, int out_size, void* d_ws, size_t ws_size,
                              hipStream_t stream)
{
    const int M   = N_NODES;
    const int NE  = N_EDGES;
    const int nnz = NNZ_C;

    const float* x   = (const float*)d_in[0];
    const int*  nidx = (const int*)d_in[1];
    const int*  eidx = nidx + nnz;
    const float* W1  = (const float*)d_in[2];
    const float* b1  = (const float*)d_in[3];
    const float* W2  = (const float*)d_in[4];
    const float* b2  = (const float*)d_in[5];
    const float* W3  = (const float*)d_in[6];
    const float* b3  = (const float*)d_in[7];
    const float* g1  = (const float*)d_in[8];
    const float* bt1 = (const float*)d_in[9];
    const float* g2  = (const float*)d_in[10];
    const float* bt2 = (const float*)d_in[11];
    const float* g3  = (const float*)d_in[12];
    const float* bt3 = (const float*)d_in[13];
    const float* Wc1 = (const float*)d_in[14];
    const float* bc1 = (const float*)d_in[15];
    const float* Wc2 = (const float*)d_in[16];
    const float* bc2 = (const float*)d_in[17];
    float* out = (float*)d_out;

    // ---- workspace carve-up ----
    const size_t SZ = (size_t)M * 128 * sizeof(float);   // 51.2 MB
    const size_t HS = (size_t)M * 128 * sizeof(u16);     // 25.6 MB
    char* ws = (char*)d_ws;
    float* A  = (float*)(ws);                 // GEMM out / node agg (fp32)
    float* B  = (float*)(ws + SZ);            // edge features (fp32)
    u16*   Xb = (u16*)(ws + SZ);              // bf16 X — aliases B (dead after GEMM0)
    u16*   H  = (u16*)(ws + 2 * SZ);          // post-BN activations (bf16)
    int* ib = (int*)(ws + 2 * SZ + HS);
    int*   cntD    = ib;
    int*   cntB    = ib + 100000;
    int*   rowptrD = ib + 200000;
    int*   rowptrB = ib + 300002;
    int*   curD    = ib + 400004;
    int*   curB    = ib + 500004;
    int*   colD    = ib + 600004;
    int*   colB    = ib + 1200004;
    int*   partD   = ib + 1800004;
    int*   partB   = ib + 1800404;
    float* fb = (float*)(ib + 1800804);
    float* Dinv   = fb;
    float* Binv   = fb + 100000;
    float* gsum   = fb + 200000;
    float* gsq    = fb + 200128;
    float* bscale = fb + 200256;
    float* bshift = fb + 200384;
    u16* wbuf = (u16*)(fb + 200512);
    u16* W1b = wbuf;                          // 256*128 bf16
    u16* W2b = wbuf + 32768;                  // 128*128
    u16* W3b = wbuf + 49152;                  // 128*128

    const int nb_scan      = (M + 255) / 256;
    const int ntiles       = (M + 127) / 128;            // 782
    const int stats_blocks = (M + 127) / 128;
    const int apply_blocks = (M * 32) / 256;
    const int gather_blkN  = (M + 3) / 4;
    const int gather_blkE  = (NE + 3) / 4;

    // ---- CSR build + weight/X conversion ----
    hipMemsetAsync(cntD, 0, 800000, stream);
    degrees_kernel<<<(nnz + 255) / 256, 256, 0, stream>>>(nidx, eidx, cntD, cntB, nnz);
    make_inv_kernel<<<(M + 255) / 256, 256, 0, stream>>>(cntD, cntB, Dinv, Binv, M);
    block_partials<<<nb_scan, 256, 0, stream>>>(cntD, partD, M);
    block_partials<<<nb_scan, 256, 0, stream>>>(cntB, partB, NE);
    scan_partials<<<1, 512, 0, stream>>>(partD, nb_scan);
    scan_partials<<<1, 512, 0, stream>>>(partB, nb_scan);
    scan_final<<<nb_scan, 256, 0, stream>>>(cntD, partD, rowptrD, curD, M);
    scan_final<<<nb_scan, 256, 0, stream>>>(cntB, partB, rowptrB, curB, NE);
    fill_csr<<<(nnz + 255) / 256, 256, 0, stream>>>(nidx, eidx, curB, curD, colB, colD, nnz);

    f32_to_bf16_k<<<(M * 256 / 4 + 255) / 256, 256, 0, stream>>>(x, Xb, M * 256 / 4);
    f32_to_bf16_k<<<32, 256, 0, stream>>>(W1, W1b, 256 * 128 / 4);
    f32_to_bf16_k<<<16, 256, 0, stream>>>(W2, W2b, 128 * 128 / 4);
    f32_to_bf16_k<<<16, 256, 0, stream>>>(W3, W3b, 128 * 128 / 4);

    const float* bin[3]  = { b1, b2, b3 };
    const float* gin[3]  = { g1, g2, g3 };
    const float* btin[3] = { bt1, bt2, bt3 };
    const u16*   Wbf[3]  = { W1b, W2b, W3b };

    for (int L = 0; L < 3; L++) {
        if (L == 0)
            gemm_mfma<256><<<512, 256, 0, stream>>>(Xb, Wbf[L], A, M, ntiles);
        else
            gemm_mfma<128><<<512, 256, 0, stream>>>(H, Wbf[L], A, M, ntiles);
        // edge aggregation (overwrites Xb region on L==0 — Xb dead by then)
        gather_rows<<<gather_blkE, 256, 0, stream>>>(A, rowptrB, colB, Binv, B, NE);
        gather_rows<<<gather_blkN, 256, 0, stream>>>(B, rowptrD, colD, Dinv, A, M);
        hipMemsetAsync(gsum, 0, 1024, stream);
        bn_stats<<<stats_blocks, 256, 0, stream>>>(A, bin[L], gsum, gsq, M);
        bn_finalize<<<1, 128, 0, stream>>>(gsum, gsq, gin[L], btin[L], bscale, bshift, 1.0f / (float)M);
        bn_apply<<<apply_blocks, 256, 0, stream>>>(A, bin[L], bscale, bshift, H, M);
    }

    classifier_kernel<<<M / 4, 256, 0, stream>>>(H, Wc1, bc1, Wc2, bc2, out, M);
}

// Round 4
// 1034.085 us; speedup vs baseline: 4.0043x; 1.1404x over previous
//
#include <hip/hip_runtime.h>

#define N_NODES 100000
#define N_EDGES 100000
#define NNZ_C   600000

typedef unsigned short u16;
typedef __attribute__((ext_vector_type(8))) short short8;
typedef __attribute__((ext_vector_type(4))) float float4v;

__device__ __forceinline__ void atomAddF(float* p, float v) {
    unsafeAtomicAdd(p, v);   // hardware global_atomic_add_f32 on gfx950
}

__device__ __forceinline__ u16 f2bf(float f) {     // RNE fp32 -> bf16
    union { float f; unsigned int i; } x; x.f = f;
    unsigned int r = x.i + 0x7FFFu + ((x.i >> 16) & 1u);
    return (u16)(r >> 16);
}
__device__ __forceinline__ float bf2f(u16 u) {
    union { float f; unsigned int i; } x; x.i = ((unsigned int)u) << 16; return x.f;
}

// ---------------- fp32 -> bf16 conversion -----------------------------------
__global__ __launch_bounds__(256) void f32_to_bf16_k(
    const float* __restrict__ src, u16* __restrict__ dst, int n4)
{
    int i = blockIdx.x * 256 + threadIdx.x;
    if (i < n4) {
        float4 v = *(const float4*)(src + (size_t)i * 4);
        ushort4 o;
        o.x = f2bf(v.x); o.y = f2bf(v.y); o.z = f2bf(v.z); o.w = f2bf(v.w);
        *(ushort4*)(dst + (size_t)i * 4) = o;
    }
}

// ---------------- degree histograms -----------------------------------------
__global__ __launch_bounds__(256) void degrees_kernel(
    const int* __restrict__ nidx, const int* __restrict__ eidx,
    int* __restrict__ cd, int* __restrict__ cb, int nnz)
{
    int i = blockIdx.x * 256 + threadIdx.x;
    if (i < nnz) {
        atomicAdd(&cd[nidx[i]], 1);
        atomicAdd(&cb[eidx[i]], 1);
    }
}

__global__ __launch_bounds__(256) void make_inv_kernel(
    const int* __restrict__ cd, const int* __restrict__ cb,
    float* __restrict__ dinv, float* __restrict__ binv, int n)
{
    int i = blockIdx.x * 256 + threadIdx.x;
    if (i < n) {
        int d = cd[i], b = cb[i];
        dinv[i] = d > 0 ? 1.0f / (float)d : 0.0f;
        binv[i] = b > 0 ? 1.0f / (float)b : 0.0f;
    }
}

// ---------------- CSR build: block scan pipeline -----------------------------
__global__ __launch_bounds__(256) void block_partials(
    const int* __restrict__ cnt, int* __restrict__ part, int n)
{
    __shared__ int s[256];
    int i = blockIdx.x * 256 + threadIdx.x;
    s[threadIdx.x] = (i < n) ? cnt[i] : 0;
    __syncthreads();
#pragma unroll
    for (int off = 128; off > 0; off >>= 1) {
        if (threadIdx.x < off) s[threadIdx.x] += s[threadIdx.x + off];
        __syncthreads();
    }
    if (threadIdx.x == 0) part[blockIdx.x] = s[0];
}

__global__ __launch_bounds__(512) void scan_partials(int* __restrict__ part, int nb)
{
    __shared__ int s[512];
    int t = threadIdx.x;
    s[t] = (t < nb) ? part[t] : 0;
    __syncthreads();
#pragma unroll
    for (int off = 1; off < 512; off <<= 1) {
        int v = (t >= off) ? s[t - off] : 0;
        __syncthreads();
        s[t] += v;
        __syncthreads();
    }
    if (t < nb) part[t] = s[t];   // inclusive block sums
}

__global__ __launch_bounds__(256) void scan_final(
    const int* __restrict__ cnt, const int* __restrict__ part,
    int* __restrict__ rowptr, int* __restrict__ cursor, int n)
{
    __shared__ int s[256];
    int i = blockIdx.x * 256 + threadIdx.x;
    int v = (i < n) ? cnt[i] : 0;
    s[threadIdx.x] = v;
    __syncthreads();
#pragma unroll
    for (int off = 1; off < 256; off <<= 1) {
        int t = (threadIdx.x >= off) ? s[threadIdx.x - off] : 0;
        __syncthreads();
        s[threadIdx.x] += t;
        __syncthreads();
    }
    int base = (blockIdx.x > 0) ? part[blockIdx.x - 1] : 0;
    if (i < n) {
        int excl = base + s[threadIdx.x] - v;
        rowptr[i] = excl;
        cursor[i] = excl;
        if (i == n - 1) rowptr[n] = base + s[threadIdx.x];
    }
}

__global__ __launch_bounds__(256) void fill_csr(
    const int* __restrict__ nidx, const int* __restrict__ eidx,
    int* __restrict__ curB, int* __restrict__ curD,
    int* __restrict__ colB, int* __restrict__ colD, int nnz)
{
    int i = blockIdx.x * 256 + threadIdx.x;
    if (i < nnz) {
        int n = nidx[i], e = eidx[i];
        colB[atomicAdd(&curB[e], 1)] = n;
        colD[atomicAdd(&curD[n], 1)] = e;
    }
}

// ---------------- bf16 MFMA GEMM: C[M,128](bf16) = A[M,K](bf16) @ W[K,128] --
// Block 256 (4 waves), tile 128 rows, wave = 32 rows x 128 cols = 2x8 MFMAs
// of 16x16x32 per 32-k step. W staged per 128-k chunk, rotation-swizzled.
// A-frags straight from global (16-B chunks). Epilogue: C-frags -> per-wave
// LDS tile (stride 136 bf16 = 272 B, 16-B aligned) -> coalesced dwordx4 rows.
template<int KDIM>
__global__ __launch_bounds__(256) void gemm_mfma(
    const u16* __restrict__ A, const u16* __restrict__ Wb,
    u16* __restrict__ C, int M)
{
    __shared__ __attribute__((aligned(16))) u16 Wt[128 * 128];   // 32 KB
    __shared__ __attribute__((aligned(16))) u16 tb[4][16][136];  // 17 KB
    const int tid = threadIdx.x;
    const int wave = tid >> 6, lane = tid & 63;
    const int l16 = lane & 15, quad = lane >> 4;
    const int rowt = blockIdx.x * 128 + wave * 32;
    const int r0 = rowt + l16, r1 = rowt + 16 + l16;
    const bool v0 = r0 < M, v1 = r1 < M;
    const u16* a0p = A + (size_t)(v0 ? r0 : 0) * KDIM + quad * 8;
    const u16* a1p = A + (size_t)(v1 ? r1 : 0) * KDIM + quad * 8;

    float4v acc[2][8];
#pragma unroll
    for (int g = 0; g < 2; g++)
#pragma unroll
        for (int c = 0; c < 8; c++) acc[g][c] = (float4v)0.0f;

    for (int kc = 0; kc < KDIM; kc += 128) {
        if (kc) __syncthreads();           // protect Wt reuse across chunks
        // stage Wt[n][rot(kb,n)] = Wb[kc+k][n]; coalesced uint2 global reads
        for (int i = tid * 4; i < 128 * 128; i += 1024) {
            int k = i >> 7, n0 = i & 127;
            uint2 v = *(const uint2*)(Wb + (size_t)(kc + k) * 128 + n0);
            int kb = k >> 3, kin = k & 7;
            Wt[(n0 + 0) * 128 + (((kb + n0 + 0) & 15) << 3) + kin] = (u16)(v.x & 0xFFFF);
            Wt[(n0 + 1) * 128 + (((kb + n0 + 1) & 15) << 3) + kin] = (u16)(v.x >> 16);
            Wt[(n0 + 2) * 128 + (((kb + n0 + 2) & 15) << 3) + kin] = (u16)(v.y & 0xFFFF);
            Wt[(n0 + 3) * 128 + (((kb + n0 + 3) & 15) << 3) + kin] = (u16)(v.y >> 16);
        }
        __syncthreads();
        for (int k0 = 0; k0 < 128; k0 += 32) {
            short8 af0 = *(const short8*)(a0p + kc + k0);
            short8 af1 = *(const short8*)(a1p + kc + k0);
            if (!v0) af0 = (short8)(short)0;
            if (!v1) af1 = (short8)(short)0;
            const int kb = (k0 >> 3) + quad;
#pragma unroll
            for (int c = 0; c < 8; c++) {
                const int n = c * 16 + l16;
                short8 bf = *(const short8*)&Wt[n * 128 + (((kb + n) & 15) << 3)];
                acc[0][c] = __builtin_amdgcn_mfma_f32_16x16x32_bf16(af0, bf, acc[0][c], 0, 0, 0);
                acc[1][c] = __builtin_amdgcn_mfma_f32_16x16x32_bf16(af1, bf, acc[1][c], 0, 0, 0);
            }
        }
    }
    // epilogue: C/D layout (col=l16, row=quad*4+r) -> bf16 -> coalesced rows.
    // tb region is per-wave: no barriers needed, only lgkmcnt ordering.
#pragma unroll
    for (int g = 0; g < 2; g++) {
#pragma unroll
        for (int c = 0; c < 8; c++)
#pragma unroll
            for (int r = 0; r < 4; r++)
                tb[wave][quad * 4 + r][c * 16 + l16] = f2bf(acc[g][c][r]);
        asm volatile("s_waitcnt lgkmcnt(0)" ::: "memory");
#pragma unroll
        for (int j = 0; j < 4; j++) {
            int row_l = j * 4 + (lane >> 4);
            int row = rowt + g * 16 + row_l;
            if (row < M) {
                short8 vv = *(const short8*)&tb[wave][row_l][(lane & 15) * 8];
                *(short8*)(C + (size_t)row * 128 + (lane & 15) * 8) = vv;
            }
        }
        if (g == 0) asm volatile("s_waitcnt lgkmcnt(0)" ::: "memory");
    }
}

// ---------------- gather: dst[r] = wgt[r] * sum_{s in row r} src[s] (bf16) --
__global__ __launch_bounds__(256) void gather_rows_bf16(
    const u16* __restrict__ src, const int* __restrict__ rowptr,
    const int* __restrict__ col, const float* __restrict__ wgt,
    u16* __restrict__ dst, int nrows)
{
    int r = blockIdx.x * 4 + (threadIdx.x >> 6);
    if (r >= nrows) return;
    int lane = threadIdx.x & 63;
    int p0 = rowptr[r], p1 = rowptr[r + 1];
    float ax = 0.0f, ay = 0.0f;
    for (int p = p0; p < p1; p++) {
        int s = col[p];
        unsigned int v = *(const unsigned int*)&src[(size_t)s * 128 + lane * 2];
        ax += bf2f((u16)(v & 0xFFFF));
        ay += bf2f((u16)(v >> 16));
    }
    float w = wgt[r];
    unsigned int o = (unsigned int)f2bf(ax * w) | ((unsigned int)f2bf(ay * w) << 16);
    *(unsigned int*)&dst[(size_t)r * 128 + lane * 2] = o;
}

// ---------------- BN stats over v = z[row][col] + bias[col] (z bf16) --------
__global__ __launch_bounds__(256) void bn_stats(
    const u16* __restrict__ z, const float* __restrict__ bias,
    float* __restrict__ gsum, float* __restrict__ gsq, int M)
{
    __shared__ float ssum[256], ssq[256];
    int col  = threadIdx.x & 127;
    int half = threadIdx.x >> 7;
    int base = blockIdx.x * 128;
    float bc = bias[col];
    float s = 0.0f, q = 0.0f;
    for (int r = half; r < 128; r += 2) {
        int row = base + r;
        if (row < M) {
            float v = bf2f(z[(size_t)row * 128 + col]) + bc;
            s += v; q += v * v;
        }
    }
    ssum[threadIdx.x] = s; ssq[threadIdx.x] = q;
    __syncthreads();
    if (half == 0) {
        atomAddF(&gsum[col], ssum[col] + ssum[col + 128]);
        atomAddF(&gsq[col],  ssq[col]  + ssq[col + 128]);
    }
}

__global__ void bn_finalize(
    const float* __restrict__ gsum, const float* __restrict__ gsq,
    const float* __restrict__ g, const float* __restrict__ bt,
    float* __restrict__ scale, float* __restrict__ shift, float invM)
{
    int c = threadIdx.x;  // 128 threads
    float mean = gsum[c] * invM;
    float var  = gsq[c] * invM - mean * mean;
    if (var < 0.0f) var = 0.0f;
    float sc = g[c] * rsqrtf(var + 1e-5f);
    scale[c] = sc;
    shift[c] = bt[c] - mean * sc;
}

// ---------------- BN apply + ReLU: bf16 z -> bf16 H -------------------------
__global__ __launch_bounds__(256) void bn_apply(
    const u16* __restrict__ z, const float* __restrict__ bias,
    const float* __restrict__ scale, const float* __restrict__ shift,
    u16* __restrict__ h, int M)
{
    int t = blockIdx.x * 256 + threadIdx.x;
    int row = t >> 5;
    if (row >= M) return;
    int c4 = (t & 31) * 4;
    uint2 zv = *(const uint2*)&z[(size_t)row * 128 + c4];
    float z0 = bf2f((u16)(zv.x & 0xFFFF)), z1 = bf2f((u16)(zv.x >> 16));
    float z2 = bf2f((u16)(zv.y & 0xFFFF)), z3 = bf2f((u16)(zv.y >> 16));
    float4 bv = *(const float4*)&bias[c4];
    float4 sc = *(const float4*)&scale[c4];
    float4 sh = *(const float4*)&shift[c4];
    ushort4 o;
    o.x = f2bf(fmaxf((z0 + bv.x) * sc.x + sh.x, 0.0f));
    o.y = f2bf(fmaxf((z1 + bv.y) * sc.y + sh.y, 0.0f));
    o.z = f2bf(fmaxf((z2 + bv.z) * sc.z + sh.z, 0.0f));
    o.w = f2bf(fmaxf((z3 + bv.w) * sc.w + sh.w, 0.0f));
    *(ushort4*)&h[(size_t)row * 128 + c4] = o;
}

// ---------------- MFMA classifier: out = relu(H@Wc1+bc1)@Wc2+bc2 ------------
// Layer1: K=128,N=64 via 16x16x32 MFMA (Wc1^T rotation-swizzled in LDS).
// Hidden relu'd to per-wave LDS (stride 72 bf16 = 144 B, 16-B aligned).
// Layer2: K=64, N=16 (cols >=10 zero-padded).
__global__ __launch_bounds__(256) void classifier_mfma(
    const u16* __restrict__ H, const float* __restrict__ Wc1,
    const float* __restrict__ bc1, const float* __restrict__ Wc2,
    const float* __restrict__ bc2, float* __restrict__ out, int M)
{
    __shared__ __attribute__((aligned(16))) u16 W1t[64 * 128];   // 16 KB
    __shared__ __attribute__((aligned(16))) u16 W2t[16 * 64];    // 2 KB
    __shared__ __attribute__((aligned(16))) u16 hs[128][72];     // 18.4 KB
    const int tid = threadIdx.x;
    for (int i = tid; i < 64 * 128; i += 256) {   // i = k*64 + n
        int k = i >> 6, n = i & 63;
        int kb = k >> 3, kin = k & 7;
        W1t[n * 128 + (((kb + n) & 15) << 3) + kin] = f2bf(Wc1[i]);
    }
    for (int i = tid; i < 16 * 64; i += 256) {    // i = k*16 + n
        int k = i >> 4, n = i & 15;
        W2t[n * 64 + k] = (n < 10) ? f2bf(Wc2[k * 10 + n]) : (u16)0;
    }
    __syncthreads();

    const int wave = tid >> 6, lane = tid & 63;
    const int l16 = lane & 15, quad = lane >> 4;
    const int rowt = blockIdx.x * 128 + wave * 32;
    const int r0 = rowt + l16, r1 = rowt + 16 + l16;
    const bool v0 = r0 < M, v1 = r1 < M;
    const u16* a0p = H + (size_t)(v0 ? r0 : 0) * 128 + quad * 8;
    const u16* a1p = H + (size_t)(v1 ? r1 : 0) * 128 + quad * 8;

    float4v acc[2][4];
#pragma unroll
    for (int g = 0; g < 2; g++)
#pragma unroll
        for (int c = 0; c < 4; c++) acc[g][c] = (float4v)0.0f;

#pragma unroll
    for (int k0 = 0; k0 < 128; k0 += 32) {
        short8 af0 = *(const short8*)(a0p + k0);
        short8 af1 = *(const short8*)(a1p + k0);
        if (!v0) af0 = (short8)(short)0;
        if (!v1) af1 = (short8)(short)0;
        const int kb = (k0 >> 3) + quad;
#pragma unroll
        for (int c = 0; c < 4; c++) {
            const int n = c * 16 + l16;
            short8 bf = *(const short8*)&W1t[n * 128 + (((kb + n) & 15) << 3)];
            acc[0][c] = __builtin_amdgcn_mfma_f32_16x16x32_bf16(af0, bf, acc[0][c], 0, 0, 0);
            acc[1][c] = __builtin_amdgcn_mfma_f32_16x16x32_bf16(af1, bf, acc[1][c], 0, 0, 0);
        }
    }
    // hidden -> per-wave LDS rows (wave*32 .. +31); same-wave, no barrier
#pragma unroll
    for (int g = 0; g < 2; g++)
#pragma unroll
        for (int c = 0; c < 4; c++) {
            float b = bc1[c * 16 + l16];
#pragma unroll
            for (int r = 0; r < 4; r++)
                hs[wave * 32 + g * 16 + quad * 4 + r][c * 16 + l16] =
                    f2bf(fmaxf(acc[g][c][r] + b, 0.0f));
        }
    asm volatile("s_waitcnt lgkmcnt(0)" ::: "memory");

    float4v a2[2];
    a2[0] = (float4v)0.0f; a2[1] = (float4v)0.0f;
#pragma unroll
    for (int k0 = 0; k0 < 64; k0 += 32) {
        short8 bf = *(const short8*)&W2t[l16 * 64 + k0 + quad * 8];
#pragma unroll
        for (int g = 0; g < 2; g++) {
            short8 af = *(const short8*)&hs[wave * 32 + g * 16 + l16][k0 + quad * 8];
            a2[g] = __builtin_amdgcn_mfma_f32_16x16x32_bf16(af, bf, a2[g], 0, 0, 0);
        }
    }
    if (l16 < 10) {
        float b2 = bc2[l16];
#pragma unroll
        for (int g = 0; g < 2; g++)
#pragma unroll
            for (int r = 0; r < 4; r++) {
                int row = rowt + g * 16 + quad * 4 + r;
                if (row < M) out[(size_t)row * 10 + l16] = a2[g][r] + b2;
            }
    }
}

// ---------------- launch ----------------------------------------------------
extern "C" void kernel_launch(void* const* d_in, const int* in_sizes, int n_in,
                              void* d_out, int out_size, void* d_ws, size_t ws_size,
                              hipStream_t stream)
{
    const int M   = N_NODES;
    const int NE  = N_EDGES;
    const int nnz = NNZ_C;

    const float* x   = (const float*)d_in[0];
    const int*  nidx = (const int*)d_in[1];
    const int*  eidx = nidx + nnz;
    const float* W1  = (const float*)d_in[2];
    const float* b1  = (const float*)d_in[3];
    const float* W2  = (const float*)d_in[4];
    const float* b2  = (const float*)d_in[5];
    const float* W3  = (const float*)d_in[6];
    const float* b3  = (const float*)d_in[7];
    const float* g1  = (const float*)d_in[8];
    const float* bt1 = (const float*)d_in[9];
    const float* g2  = (const float*)d_in[10];
    const float* bt2 = (const float*)d_in[11];
    const float* g3  = (const float*)d_in[12];
    const float* bt3 = (const float*)d_in[13];
    const float* Wc1 = (const float*)d_in[14];
    const float* bc1 = (const float*)d_in[15];
    const float* Wc2 = (const float*)d_in[16];
    const float* bc2 = (const float*)d_in[17];
    float* out = (float*)d_out;

    // ---- workspace carve-up (all features bf16) ----
    const size_t SZH = (size_t)M * 128 * sizeof(u16);   // 25.6 MB
    const size_t SZX = (size_t)M * 256 * sizeof(u16);   // 51.2 MB
    char* ws = (char*)d_ws;
    u16* Y  = (u16*)(ws);                    // GEMM output y (bf16)
    u16* Xb = (u16*)(ws + SZH);              // bf16 X; E aliases (X dead post-GEMM0)
    u16* E  = Xb;                            // edge features (bf16)
    u16* Z  = (u16*)(ws + SZH + SZX);        // node agg (bf16)
    u16* Hh = (u16*)(ws + 2 * SZH + SZX);    // post-BN activations (bf16)
    int* ib = (int*)(ws + 3 * SZH + SZX);
    int*   cntD    = ib;
    int*   cntB    = ib + 100000;
    int*   rowptrD = ib + 200000;
    int*   rowptrB = ib + 300002;
    int*   curD    = ib + 400004;
    int*   curB    = ib + 500004;
    int*   colD    = ib + 600004;
    int*   colB    = ib + 1200004;
    int*   partD   = ib + 1800004;
    int*   partB   = ib + 1800404;
    float* fb = (float*)(ib + 1800804);
    float* Dinv   = fb;
    float* Binv   = fb + 100000;
    float* gsum   = fb + 200000;
    float* gsq    = fb + 200128;
    float* bscale = fb + 200256;
    float* bshift = fb + 200384;
    u16* wbuf = (u16*)(fb + 200512);
    u16* W1b = wbuf;                          // 256*128 bf16
    u16* W2b = wbuf + 32768;                  // 128*128
    u16* W3b = wbuf + 49152;                  // 128*128

    const int nb_scan      = (M + 255) / 256;
    const int ntiles       = (M + 127) / 128;            // 782
    const int stats_blocks = (M + 127) / 128;
    const int apply_blocks = (M * 32) / 256;
    const int gather_blkN  = (M + 3) / 4;
    const int gather_blkE  = (NE + 3) / 4;

    // ---- CSR build + weight/X conversion ----
    hipMemsetAsync(cntD, 0, 800000, stream);
    degrees_kernel<<<(nnz + 255) / 256, 256, 0, stream>>>(nidx, eidx, cntD, cntB, nnz);
    make_inv_kernel<<<(M + 255) / 256, 256, 0, stream>>>(cntD, cntB, Dinv, Binv, M);
    block_partials<<<nb_scan, 256, 0, stream>>>(cntD, partD, M);
    block_partials<<<nb_scan, 256, 0, stream>>>(cntB, partB, NE);
    scan_partials<<<1, 512, 0, stream>>>(partD, nb_scan);
    scan_partials<<<1, 512, 0, stream>>>(partB, nb_scan);
    scan_final<<<nb_scan, 256, 0, stream>>>(cntD, partD, rowptrD, curD, M);
    scan_final<<<nb_scan, 256, 0, stream>>>(cntB, partB, rowptrB, curB, NE);
    fill_csr<<<(nnz + 255) / 256, 256, 0, stream>>>(nidx, eidx, curB, curD, colB, colD, nnz);

    f32_to_bf16_k<<<(M * 256 / 4 + 255) / 256, 256, 0, stream>>>(x, Xb, M * 256 / 4);
    f32_to_bf16_k<<<32, 256, 0, stream>>>(W1, W1b, 256 * 128 / 4);
    f32_to_bf16_k<<<16, 256, 0, stream>>>(W2, W2b, 128 * 128 / 4);
    f32_to_bf16_k<<<16, 256, 0, stream>>>(W3, W3b, 128 * 128 / 4);

    const float* bin[3]  = { b1, b2, b3 };
    const float* gin[3]  = { g1, g2, g3 };
    const float* btin[3] = { bt1, bt2, bt3 };
    const u16*   Wbf[3]  = { W1b, W2b, W3b };

    for (int L = 0; L < 3; L++) {
        if (L == 0)
            gemm_mfma<256><<<ntiles, 256, 0, stream>>>(Xb, Wbf[L], Y, M);
        else
            gemm_mfma<128><<<ntiles, 256, 0, stream>>>(Hh, Wbf[L], Y, M);
        // edge aggregation (E aliases Xb; Xb dead after GEMM0)
        gather_rows_bf16<<<gather_blkE, 256, 0, stream>>>(Y, rowptrB, colB, Binv, E, NE);
        gather_rows_bf16<<<gather_blkN, 256, 0, stream>>>(E, rowptrD, colD, Dinv, Z, M);
        hipMemsetAsync(gsum, 0, 1024, stream);
        bn_stats<<<stats_blocks, 256, 0, stream>>>(Z, bin[L], gsum, gsq, M);
        bn_finalize<<<1, 128, 0, stream>>>(gsum, gsq, gin[L], btin[L], bscale, bshift, 1.0f / (float)M);
        bn_apply<<<apply_blocks, 256, 0, stream>>>(Z, bin[L], bscale, bshift, Hh, M);
    }

    classifier_mfma<<<ntiles, 256, 0, stream>>>(Hh, Wc1, bc1, Wc2, bc2, out, M);
}

// Round 5
// 770.678 us; speedup vs baseline: 5.3729x; 1.3418x over previous
//
#include <hip/hip_runtime.h>

#define N_NODES 100000
#define N_EDGES 100000
#define NNZ_C   600000
#define CAP     32          // fixed bucket capacity; deg ~ Poisson(6), P(>32) ~ 1e-14/row

typedef unsigned short u16;
typedef __attribute__((ext_vector_type(8))) short short8;
typedef __attribute__((ext_vector_type(4))) float float4v;

__device__ __forceinline__ void atomAddF(float* p, float v) {
    unsafeAtomicAdd(p, v);
}

__device__ __forceinline__ u16 f2bf(float f) {     // RNE fp32 -> bf16
    union { float f; unsigned int i; } x; x.f = f;
    unsigned int r = x.i + 0x7FFFu + ((x.i >> 16) & 1u);
    return (u16)(r >> 16);
}
__device__ __forceinline__ float bf2f(u16 u) {
    union { float f; unsigned int i; } x; x.i = ((unsigned int)u) << 16; return x.f;
}

// ---------------- combined degree-count + bucket fill ------------------------
// cnt arrays double as cursors; after this kernel cnt[e] == degree.
__global__ __launch_bounds__(256) void fill_direct(
    const int* __restrict__ nidx, const int* __restrict__ eidx,
    int* __restrict__ cb, int* __restrict__ cd,
    int* __restrict__ colB, int* __restrict__ colD, int nnz)
{
    int i = blockIdx.x * 256 + threadIdx.x;
    if (i < nnz) {
        int n = nidx[i], e = eidx[i];
        int pb = atomicAdd(&cb[e], 1);
        if (pb < CAP) __builtin_nontemporal_store(n, &colB[(e << 5) + pb]);
        int pd = atomicAdd(&cd[n], 1);
        if (pd < CAP) __builtin_nontemporal_store(e, &colD[(n << 5) + pd]);
    }
}

__global__ __launch_bounds__(256) void make_inv_kernel(
    const int* __restrict__ cd, const int* __restrict__ cb,
    float* __restrict__ dinv, float* __restrict__ binv, int n)
{
    int i = blockIdx.x * 256 + threadIdx.x;
    if (i < n) {
        int d = cd[i], b = cb[i];
        dinv[i] = d > 0 ? 1.0f / (float)d : 0.0f;
        binv[i] = b > 0 ? 1.0f / (float)b : 0.0f;
    }
}

// ---------------- fused fp32 -> bf16 conversion (X + W1 + W2 + W3) ----------
#define XG 6400000            // X float4-groups
__global__ __launch_bounds__(256) void convert_all(
    const float* __restrict__ x,  const float* __restrict__ W1,
    const float* __restrict__ W2, const float* __restrict__ W3,
    u16* __restrict__ Xb, u16* __restrict__ W1b,
    u16* __restrict__ W2b, u16* __restrict__ W3b)
{
    int i = blockIdx.x * 256 + threadIdx.x;
    const float* src; u16* dst; int base;
    if (i < XG)              { src = x;  dst = Xb;  base = i; }
    else {
        int j = i - XG;
        if      (j <  8192)  { src = W1; dst = W1b; base = j; }
        else if (j < 12288)  { src = W2; dst = W2b; base = j - 8192; }
        else if (j < 16384)  { src = W3; dst = W3b; base = j - 12288; }
        else return;
    }
    float4 v = *(const float4*)(src + (size_t)base * 4);
    ushort4 o;
    o.x = f2bf(v.x); o.y = f2bf(v.y); o.z = f2bf(v.z); o.w = f2bf(v.w);
    *(ushort4*)(dst + (size_t)base * 4) = o;
}

// ---------------- bf16 MFMA GEMM: C[M,128](bf16) = A[M,K](bf16) @ W[K,128] --
template<int KDIM>
__global__ __launch_bounds__(256) void gemm_mfma(
    const u16* __restrict__ A, const u16* __restrict__ Wb,
    u16* __restrict__ C, int M)
{
    __shared__ __attribute__((aligned(16))) u16 Wt[128 * 128];   // 32 KB
    __shared__ __attribute__((aligned(16))) u16 tb[4][16][136];  // 17 KB
    const int tid = threadIdx.x;
    const int wave = tid >> 6, lane = tid & 63;
    const int l16 = lane & 15, quad = lane >> 4;
    const int rowt = blockIdx.x * 128 + wave * 32;
    const int r0 = rowt + l16, r1 = rowt + 16 + l16;
    const bool v0 = r0 < M, v1 = r1 < M;
    const u16* a0p = A + (size_t)(v0 ? r0 : 0) * KDIM + quad * 8;
    const u16* a1p = A + (size_t)(v1 ? r1 : 0) * KDIM + quad * 8;

    float4v acc[2][8];
#pragma unroll
    for (int g = 0; g < 2; g++)
#pragma unroll
        for (int c = 0; c < 8; c++) acc[g][c] = (float4v)0.0f;

    for (int kc = 0; kc < KDIM; kc += 128) {
        if (kc) __syncthreads();
        for (int i = tid * 4; i < 128 * 128; i += 1024) {
            int k = i >> 7, n0 = i & 127;
            uint2 v = *(const uint2*)(Wb + (size_t)(kc + k) * 128 + n0);
            int kb = k >> 3, kin = k & 7;
            Wt[(n0 + 0) * 128 + (((kb + n0 + 0) & 15) << 3) + kin] = (u16)(v.x & 0xFFFF);
            Wt[(n0 + 1) * 128 + (((kb + n0 + 1) & 15) << 3) + kin] = (u16)(v.x >> 16);
            Wt[(n0 + 2) * 128 + (((kb + n0 + 2) & 15) << 3) + kin] = (u16)(v.y & 0xFFFF);
            Wt[(n0 + 3) * 128 + (((kb + n0 + 3) & 15) << 3) + kin] = (u16)(v.y >> 16);
        }
        __syncthreads();
        for (int k0 = 0; k0 < 128; k0 += 32) {
            short8 af0 = *(const short8*)(a0p + kc + k0);
            short8 af1 = *(const short8*)(a1p + kc + k0);
            if (!v0) af0 = (short8)(short)0;
            if (!v1) af1 = (short8)(short)0;
            const int kb = (k0 >> 3) + quad;
#pragma unroll
            for (int c = 0; c < 8; c++) {
                const int n = c * 16 + l16;
                short8 bf = *(const short8*)&Wt[n * 128 + (((kb + n) & 15) << 3)];
                acc[0][c] = __builtin_amdgcn_mfma_f32_16x16x32_bf16(af0, bf, acc[0][c], 0, 0, 0);
                acc[1][c] = __builtin_amdgcn_mfma_f32_16x16x32_bf16(af1, bf, acc[1][c], 0, 0, 0);
            }
        }
    }
#pragma unroll
    for (int g = 0; g < 2; g++) {
#pragma unroll
        for (int c = 0; c < 8; c++)
#pragma unroll
            for (int r = 0; r < 4; r++)
                tb[wave][quad * 4 + r][c * 16 + l16] = f2bf(acc[g][c][r]);
        asm volatile("s_waitcnt lgkmcnt(0)" ::: "memory");
#pragma unroll
        for (int j = 0; j < 4; j++) {
            int row_l = j * 4 + (lane >> 4);
            int row = rowt + g * 16 + row_l;
            if (row < M) {
                short8 vv = *(const short8*)&tb[wave][row_l][(lane & 15) * 8];
                *(short8*)(C + (size_t)row * 128 + (lane & 15) * 8) = vv;
            }
        }
        if (g == 0) asm volatile("s_waitcnt lgkmcnt(0)" ::: "memory");
    }
}

// ---------------- gather over fixed-stride buckets --------------------------
// dst[r] = wgt[r] * sum_{s in bucket r} src[s]; lane i preloads member i
// (coalesced), __shfl-broadcast + 4-deep unroll for loads in flight.
// zp: if non-null, block 0 zeros 256 floats (gsum||gsq) for next bn_stats.
__global__ __launch_bounds__(256) void gather_fixed(
    const u16* __restrict__ src, const int* __restrict__ cnt,
    const int* __restrict__ col, const float* __restrict__ wgt,
    u16* __restrict__ dst, float* __restrict__ zp, int nrows)
{
    if (zp && blockIdx.x == 0) zp[threadIdx.x] = 0.0f;
    int r = blockIdx.x * 4 + (threadIdx.x >> 6);
    if (r >= nrows) return;
    int lane = threadIdx.x & 63;
    int c = cnt[r]; if (c > CAP) c = CAP;
    int m = (lane < c) ? col[(r << 5) + lane] : 0;
    const size_t lb = (size_t)lane * 2;
    float ax = 0.0f, ay = 0.0f;
    int j = 0;
    for (; j + 4 <= c; j += 4) {
        int s0 = __shfl(m, j),     s1 = __shfl(m, j + 1);
        int s2 = __shfl(m, j + 2), s3 = __shfl(m, j + 3);
        unsigned int a = *(const unsigned int*)&src[(size_t)s0 * 128 + lb];
        unsigned int b = *(const unsigned int*)&src[(size_t)s1 * 128 + lb];
        unsigned int e = *(const unsigned int*)&src[(size_t)s2 * 128 + lb];
        unsigned int d = *(const unsigned int*)&src[(size_t)s3 * 128 + lb];
        ax += bf2f((u16)(a & 0xFFFF)) + bf2f((u16)(b & 0xFFFF))
            + bf2f((u16)(e & 0xFFFF)) + bf2f((u16)(d & 0xFFFF));
        ay += bf2f((u16)(a >> 16)) + bf2f((u16)(b >> 16))
            + bf2f((u16)(e >> 16)) + bf2f((u16)(d >> 16));
    }
    for (; j < c; j++) {
        int s = __shfl(m, j);
        unsigned int v = *(const unsigned int*)&src[(size_t)s * 128 + lb];
        ax += bf2f((u16)(v & 0xFFFF));
        ay += bf2f((u16)(v >> 16));
    }
    float w = wgt[r];
    unsigned int o = (unsigned int)f2bf(ax * w) | ((unsigned int)f2bf(ay * w) << 16);
    *(unsigned int*)&dst[(size_t)r * 128 + lb] = o;
}

// ---------------- BN stats over v = z[row][col] + bias[col] (z bf16) --------
__global__ __launch_bounds__(256) void bn_stats(
    const u16* __restrict__ z, const float* __restrict__ bias,
    float* __restrict__ gsum, float* __restrict__ gsq, int M)
{
    __shared__ float ssum[256], ssq[256];
    int col  = threadIdx.x & 127;
    int half = threadIdx.x >> 7;
    int base = blockIdx.x * 128;
    float bc = bias[col];
    float s = 0.0f, q = 0.0f;
    for (int r = half; r < 128; r += 2) {
        int row = base + r;
        if (row < M) {
            float v = bf2f(z[(size_t)row * 128 + col]) + bc;
            s += v; q += v * v;
        }
    }
    ssum[threadIdx.x] = s; ssq[threadIdx.x] = q;
    __syncthreads();
    if (half == 0) {
        atomAddF(&gsum[col], ssum[col] + ssum[col + 128]);
        atomAddF(&gsq[col],  ssq[col]  + ssq[col + 128]);
    }
}

// ---------------- BN finalize + apply + ReLU: bf16 z -> bf16 H --------------
// Each block recomputes scale/shift from gsum/gsq (128 rsqrt — trivial) and
// folds the conv bias: o = relu(z*A + C), A = sc, C = b*sc + sh.
__global__ __launch_bounds__(256) void bn_apply(
    const u16* __restrict__ z, const float* __restrict__ bias,
    const float* __restrict__ gsum, const float* __restrict__ gsq,
    const float* __restrict__ g, const float* __restrict__ bt,
    u16* __restrict__ h, int M, float invM)
{
    __shared__ __attribute__((aligned(16))) float As[128];
    __shared__ __attribute__((aligned(16))) float Cs[128];
    int tid = threadIdx.x;
    if (tid < 128) {
        float mean = gsum[tid] * invM;
        float var  = gsq[tid] * invM - mean * mean;
        if (var < 0.0f) var = 0.0f;
        float sc = g[tid] * rsqrtf(var + 1e-5f);
        As[tid] = sc;
        Cs[tid] = (bias[tid] - mean) * sc + bt[tid];
    }
    __syncthreads();
    int t = blockIdx.x * 256 + tid;
    int row = t >> 5;
    if (row >= M) return;
    int c4 = (t & 31) * 4;
    uint2 zv = *(const uint2*)&z[(size_t)row * 128 + c4];
    float z0 = bf2f((u16)(zv.x & 0xFFFF)), z1 = bf2f((u16)(zv.x >> 16));
    float z2 = bf2f((u16)(zv.y & 0xFFFF)), z3 = bf2f((u16)(zv.y >> 16));
    float4 Av = *(const float4*)&As[c4];
    float4 Cv = *(const float4*)&Cs[c4];
    ushort4 o;
    o.x = f2bf(fmaxf(z0 * Av.x + Cv.x, 0.0f));
    o.y = f2bf(fmaxf(z1 * Av.y + Cv.y, 0.0f));
    o.z = f2bf(fmaxf(z2 * Av.z + Cv.z, 0.0f));
    o.w = f2bf(fmaxf(z3 * Av.w + Cv.w, 0.0f));
    *(ushort4*)&h[(size_t)row * 128 + c4] = o;
}

// ---------------- MFMA classifier: out = relu(H@Wc1+bc1)@Wc2+bc2 ------------
__global__ __launch_bounds__(256) void classifier_mfma(
    const u16* __restrict__ H, const float* __restrict__ Wc1,
    const float* __restrict__ bc1, const float* __restrict__ Wc2,
    const float* __restrict__ bc2, float* __restrict__ out, int M)
{
    __shared__ __attribute__((aligned(16))) u16 W1t[64 * 128];   // 16 KB
    __shared__ __attribute__((aligned(16))) u16 W2t[16 * 64];    // 2 KB
    __shared__ __attribute__((aligned(16))) u16 hs[128][72];     // 18.4 KB
    const int tid = threadIdx.x;
    for (int i = tid; i < 64 * 128; i += 256) {   // i = k*64 + n
        int k = i >> 6, n = i & 63;
        int kb = k >> 3, kin = k & 7;
        W1t[n * 128 + (((kb + n) & 15) << 3) + kin] = f2bf(Wc1[i]);
    }
    for (int i = tid; i < 16 * 64; i += 256) {    // i = k*16 + n
        int k = i >> 4, n = i & 15;
        W2t[n * 64 + k] = (n < 10) ? f2bf(Wc2[k * 10 + n]) : (u16)0;
    }
    __syncthreads();

    const int wave = tid >> 6, lane = tid & 63;
    const int l16 = lane & 15, quad = lane >> 4;
    const int rowt = blockIdx.x * 128 + wave * 32;
    const int r0 = rowt + l16, r1 = rowt + 16 + l16;
    const bool v0 = r0 < M, v1 = r1 < M;
    const u16* a0p = H + (size_t)(v0 ? r0 : 0) * 128 + quad * 8;
    const u16* a1p = H + (size_t)(v1 ? r1 : 0) * 128 + quad * 8;

    float4v acc[2][4];
#pragma unroll
    for (int g = 0; g < 2; g++)
#pragma unroll
        for (int c = 0; c < 4; c++) acc[g][c] = (float4v)0.0f;

#pragma unroll
    for (int k0 = 0; k0 < 128; k0 += 32) {
        short8 af0 = *(const short8*)(a0p + k0);
        short8 af1 = *(const short8*)(a1p + k0);
        if (!v0) af0 = (short8)(short)0;
        if (!v1) af1 = (short8)(short)0;
        const int kb = (k0 >> 3) + quad;
#pragma unroll
        for (int c = 0; c < 4; c++) {
            const int n = c * 16 + l16;
            short8 bf = *(const short8*)&W1t[n * 128 + (((kb + n) & 15) << 3)];
            acc[0][c] = __builtin_amdgcn_mfma_f32_16x16x32_bf16(af0, bf, acc[0][c], 0, 0, 0);
            acc[1][c] = __builtin_amdgcn_mfma_f32_16x16x32_bf16(af1, bf, acc[1][c], 0, 0, 0);
        }
    }
#pragma unroll
    for (int g = 0; g < 2; g++)
#pragma unroll
        for (int c = 0; c < 4; c++) {
            float b = bc1[c * 16 + l16];
#pragma unroll
            for (int r = 0; r < 4; r++)
                hs[wave * 32 + g * 16 + quad * 4 + r][c * 16 + l16] =
                    f2bf(fmaxf(acc[g][c][r] + b, 0.0f));
        }
    asm volatile("s_waitcnt lgkmcnt(0)" ::: "memory");

    float4v a2[2];
    a2[0] = (float4v)0.0f; a2[1] = (float4v)0.0f;
#pragma unroll
    for (int k0 = 0; k0 < 64; k0 += 32) {
        short8 bf = *(const short8*)&W2t[l16 * 64 + k0 + quad * 8];
#pragma unroll
        for (int g = 0; g < 2; g++) {
            short8 af = *(const short8*)&hs[wave * 32 + g * 16 + l16][k0 + quad * 8];
            a2[g] = __builtin_amdgcn_mfma_f32_16x16x32_bf16(af, bf, a2[g], 0, 0, 0);
        }
    }
    if (l16 < 10) {
        float b2 = bc2[l16];
#pragma unroll
        for (int g = 0; g < 2; g++)
#pragma unroll
            for (int r = 0; r < 4; r++) {
                int row = rowt + g * 16 + quad * 4 + r;
                if (row < M) out[(size_t)row * 10 + l16] = a2[g][r] + b2;
            }
    }
}

// ---------------- launch ----------------------------------------------------
extern "C" void kernel_launch(void* const* d_in, const int* in_sizes, int n_in,
                              void* d_out, int out_size, void* d_ws, size_t ws_size,
                              hipStream_t stream)
{
    const int M   = N_NODES;
    const int NE  = N_EDGES;
    const int nnz = NNZ_C;

    const float* x   = (const float*)d_in[0];
    const int*  nidx = (const int*)d_in[1];
    const int*  eidx = nidx + nnz;
    const float* W1  = (const float*)d_in[2];
    const float* b1  = (const float*)d_in[3];
    const float* W2  = (const float*)d_in[4];
    const float* b2  = (const float*)d_in[5];
    const float* W3  = (const float*)d_in[6];
    const float* b3  = (const float*)d_in[7];
    const float* g1  = (const float*)d_in[8];
    const float* bt1 = (const float*)d_in[9];
    const float* g2  = (const float*)d_in[10];
    const float* bt2 = (const float*)d_in[11];
    const float* g3  = (const float*)d_in[12];
    const float* bt3 = (const float*)d_in[13];
    const float* Wc1 = (const float*)d_in[14];
    const float* bc1 = (const float*)d_in[15];
    const float* Wc2 = (const float*)d_in[16];
    const float* bc2 = (const float*)d_in[17];
    float* out = (float*)d_out;

    // ---- workspace carve-up ----
    const size_t SZH = (size_t)M * 128 * sizeof(u16);   // 25.6 MB
    const size_t SZX = (size_t)M * 256 * sizeof(u16);   // 51.2 MB
    char* ws = (char*)d_ws;
    u16* Y  = (u16*)(ws);                    // GEMM output y (bf16)
    u16* Xb = (u16*)(ws + SZH);              // bf16 X; E aliases (X dead post-GEMM0)
    u16* E  = Xb;                            // edge features (bf16)
    u16* Z  = (u16*)(ws + SZH + SZX);        // node agg (bf16)
    u16* Hh = (u16*)(ws + 2 * SZH + SZX);    // post-BN activations (bf16)
    int* ib = (int*)(ws + 3 * SZH + SZX);
    int*   cb   = ib;                        // edge sizes / cursors [100000]
    int*   cd   = ib + 100000;               // node degrees / cursors
    int*   colB = ib + 200000;               // edge -> nodes, CAP-stride [3.2M]
    int*   colD = ib + 200000 + NE * CAP;    // node -> edges, CAP-stride [3.2M]
    float* fb = (float*)(ib + 200000 + (NE + M) * CAP);
    float* Dinv = fb;
    float* Binv = fb + 100000;
    float* gsum = fb + 200000;               // [128]; gsq contiguous after
    float* gsq  = fb + 200128;
    u16* wbuf = (u16*)(fb + 200256);
    u16* W1b = wbuf;                         // 256*128 bf16
    u16* W2b = wbuf + 32768;                 // 128*128
    u16* W3b = wbuf + 49152;                 // 128*128

    const int ntiles       = (M + 127) / 128;
    const int stats_blocks = (M + 127) / 128;
    const int apply_blocks = (M * 32) / 256;
    const int gather_blkN  = (M + 3) / 4;
    const int gather_blkE  = (NE + 3) / 4;

    // ---- index preprocessing: one memset + one scatter kernel ----
    hipMemsetAsync(cb, 0, 800000, stream);   // cb + cd
    fill_direct<<<(nnz + 255) / 256, 256, 0, stream>>>(nidx, eidx, cb, cd, colB, colD, nnz);
    make_inv_kernel<<<(M + 255) / 256, 256, 0, stream>>>(cd, cb, Dinv, Binv, M);
    convert_all<<<(XG + 16384) / 256, 256, 0, stream>>>(x, W1, W2, W3, Xb, W1b, W2b, W3b);

    const float* bin[3]  = { b1, b2, b3 };
    const float* gin[3]  = { g1, g2, g3 };
    const float* btin[3] = { bt1, bt2, bt3 };
    const u16*   Wbf[3]  = { W1b, W2b, W3b };

    for (int L = 0; L < 3; L++) {
        if (L == 0)
            gemm_mfma<256><<<ntiles, 256, 0, stream>>>(Xb, Wbf[L], Y, M);
        else
            gemm_mfma<128><<<ntiles, 256, 0, stream>>>(Hh, Wbf[L], Y, M);
        // edge aggregation (E aliases Xb; Xb dead after GEMM0)
        gather_fixed<<<gather_blkE, 256, 0, stream>>>(Y, cb, colB, Binv, E, nullptr, NE);
        // node aggregation; block 0 zeros gsum||gsq for the stats pass
        gather_fixed<<<gather_blkN, 256, 0, stream>>>(E, cd, colD, Dinv, Z, gsum, M);
        bn_stats<<<stats_blocks, 256, 0, stream>>>(Z, bin[L], gsum, gsq, M);
        bn_apply<<<apply_blocks, 256, 0, stream>>>(Z, bin[L], gsum, gsq, gin[L], btin[L],
                                                   Hh, M, 1.0f / (float)M);
    }

    classifier_mfma<<<ntiles, 256, 0, stream>>>(Hh, Wc1, bc1, Wc2, bc2, out, M);
}

// Round 6
// 725.057 us; speedup vs baseline: 5.7110x; 1.0629x over previous
//
#include <hip/hip_runtime.h>

#define N_NODES 100000
#define N_EDGES 100000
#define NNZ_C   600000
#define CAP     16          // bucket = exactly one 64-B line; overflow list handles tail
#define OVF_MAX 4096

typedef unsigned short u16;
typedef __attribute__((ext_vector_type(8))) short short8;
typedef __attribute__((ext_vector_type(4))) float float4v;

__device__ __forceinline__ void atomAddF(float* p, float v) {
    unsafeAtomicAdd(p, v);
}

__device__ __forceinline__ u16 f2bf(float f) {     // RNE fp32 -> bf16
    union { float f; unsigned int i; } x; x.f = f;
    unsigned int r = x.i + 0x7FFFu + ((x.i >> 16) & 1u);
    return (u16)(r >> 16);
}
__device__ __forceinline__ float bf2f(u16 u) {
    union { float f; unsigned int i; } x; x.i = ((unsigned int)u) << 16; return x.f;
}

__device__ __forceinline__ short8 cvt_frag(float4 a, float4 b) {
    union { short8 s; u16 u[8]; } o;
    o.u[0] = f2bf(a.x); o.u[1] = f2bf(a.y); o.u[2] = f2bf(a.z); o.u[3] = f2bf(a.w);
    o.u[4] = f2bf(b.x); o.u[5] = f2bf(b.y); o.u[6] = f2bf(b.z); o.u[7] = f2bf(b.w);
    return o.s;
}

// relu(z*A + C) per element; A/C indexed by the fragment's k offset
__device__ __forceinline__ short8 bn_frag(short8 raw, float4 A0, float4 A1,
                                          float4 C0, float4 C1) {
    union { short8 s; u16 u[8]; } in; in.s = raw;
    union { short8 s; u16 u[8]; } o;
    o.u[0] = f2bf(fmaxf(bf2f(in.u[0]) * A0.x + C0.x, 0.0f));
    o.u[1] = f2bf(fmaxf(bf2f(in.u[1]) * A0.y + C0.y, 0.0f));
    o.u[2] = f2bf(fmaxf(bf2f(in.u[2]) * A0.z + C0.z, 0.0f));
    o.u[3] = f2bf(fmaxf(bf2f(in.u[3]) * A0.w + C0.w, 0.0f));
    o.u[4] = f2bf(fmaxf(bf2f(in.u[4]) * A1.x + C1.x, 0.0f));
    o.u[5] = f2bf(fmaxf(bf2f(in.u[5]) * A1.y + C1.y, 0.0f));
    o.u[6] = f2bf(fmaxf(bf2f(in.u[6]) * A1.z + C1.z, 0.0f));
    o.u[7] = f2bf(fmaxf(bf2f(in.u[7]) * A1.w + C1.w, 0.0f));
    return o.s;
}

// ---------------- combined degree-count + bucket fill (CAP=16 + overflow) ---
__global__ __launch_bounds__(256) void fill_direct(
    const int* __restrict__ nidx, const int* __restrict__ eidx,
    int* __restrict__ cb, int* __restrict__ cd,
    int* __restrict__ colB, int* __restrict__ colD,
    uint2* __restrict__ ovfB, uint2* __restrict__ ovfD,
    int* __restrict__ ovfCntB, int* __restrict__ ovfCntD, int nnz)
{
    int i = blockIdx.x * 256 + threadIdx.x;
    if (i < nnz) {
        int n = nidx[i], e = eidx[i];
        int pb = atomicAdd(&cb[e], 1);
        if (pb < CAP) colB[(e << 4) + pb] = n;
        else { int o = atomicAdd(ovfCntB, 1); if (o < OVF_MAX) ovfB[o] = make_uint2((unsigned)e, (unsigned)n); }
        int pd = atomicAdd(&cd[n], 1);
        if (pd < CAP) colD[(n << 4) + pd] = e;
        else { int o = atomicAdd(ovfCntD, 1); if (o < OVF_MAX) ovfD[o] = make_uint2((unsigned)n, (unsigned)e); }
    }
}

__global__ __launch_bounds__(256) void make_inv_kernel(
    const int* __restrict__ cd, const int* __restrict__ cb,
    float* __restrict__ dinv, float* __restrict__ binv, int n)
{
    int i = blockIdx.x * 256 + threadIdx.x;
    if (i < n) {
        int d = cd[i], b = cb[i];
        dinv[i] = d > 0 ? 1.0f / (float)d : 0.0f;
        binv[i] = b > 0 ? 1.0f / (float)b : 0.0f;
    }
}

// ---------------- fp32 -> bf16 conversion (weights only) --------------------
__global__ __launch_bounds__(256) void convert_w(
    const float* __restrict__ W1, const float* __restrict__ W2,
    const float* __restrict__ W3, u16* __restrict__ W1b,
    u16* __restrict__ W2b, u16* __restrict__ W3b)
{
    int i = blockIdx.x * 256 + threadIdx.x;
    const float* src; u16* dst; int base;
    if      (i <  8192) { src = W1; dst = W1b; base = i; }
    else if (i < 12288) { src = W2; dst = W2b; base = i - 8192; }
    else if (i < 16384) { src = W3; dst = W3b; base = i - 12288; }
    else return;
    float4 v = *(const float4*)(src + (size_t)base * 4);
    ushort4 o;
    o.x = f2bf(v.x); o.y = f2bf(v.y); o.z = f2bf(v.z); o.w = f2bf(v.w);
    *(ushort4*)(dst + (size_t)base * 4) = o;
}

// ---------------- bf16 MFMA GEMM with fused A-path preprocessing ------------
// AMODE 0: A is bf16, direct.  1: A is fp32, convert in-register (GEMM0).
// 2: A is bf16 pre-BN z; apply relu(z*As+Cs) per k-column (fused BN+ReLU).
template<int KDIM, int AMODE>
__global__ __launch_bounds__(256) void gemm_mfma(
    const void* __restrict__ Aptr, const u16* __restrict__ Wb,
    u16* __restrict__ C, int M,
    const float* __restrict__ gsum, const float* __restrict__ gsq,
    const float* __restrict__ bias, const float* __restrict__ gam,
    const float* __restrict__ bet, float invM)
{
    __shared__ __attribute__((aligned(16))) u16 Wt[128 * 128];   // 32 KB
    __shared__ __attribute__((aligned(16))) u16 tb[4][16][136];  // 17 KB
    __shared__ __attribute__((aligned(16))) float As[128];
    __shared__ __attribute__((aligned(16))) float Cs[128];
    const int tid = threadIdx.x;
    if (AMODE == 2 && tid < 128) {
        float mean = gsum[tid] * invM;
        float var  = gsq[tid] * invM - mean * mean;
        if (var < 0.0f) var = 0.0f;
        float sc = gam[tid] * rsqrtf(var + 1e-5f);
        As[tid] = sc;
        Cs[tid] = (bias[tid] - mean) * sc + bet[tid];
    }
    const int wave = tid >> 6, lane = tid & 63;
    const int l16 = lane & 15, quad = lane >> 4;
    const int rowt = blockIdx.x * 128 + wave * 32;
    const int r0 = rowt + l16, r1 = rowt + 16 + l16;
    const bool v0 = r0 < M, v1 = r1 < M;
    const u16*   Ab = (const u16*)Aptr;
    const float* Af = (const float*)Aptr;
    const size_t rb0 = (size_t)(v0 ? r0 : 0) * KDIM + quad * 8;
    const size_t rb1 = (size_t)(v1 ? r1 : 0) * KDIM + quad * 8;

    float4v acc[2][8];
#pragma unroll
    for (int g = 0; g < 2; g++)
#pragma unroll
        for (int c = 0; c < 8; c++) acc[g][c] = (float4v)0.0f;

    for (int kc = 0; kc < KDIM; kc += 128) {
        if (kc) __syncthreads();
        for (int i = tid * 4; i < 128 * 128; i += 1024) {
            int k = i >> 7, n0 = i & 127;
            uint2 v = *(const uint2*)(Wb + (size_t)(kc + k) * 128 + n0);
            int kb = k >> 3, kin = k & 7;
            Wt[(n0 + 0) * 128 + (((kb + n0 + 0) & 15) << 3) + kin] = (u16)(v.x & 0xFFFF);
            Wt[(n0 + 1) * 128 + (((kb + n0 + 1) & 15) << 3) + kin] = (u16)(v.x >> 16);
            Wt[(n0 + 2) * 128 + (((kb + n0 + 2) & 15) << 3) + kin] = (u16)(v.y & 0xFFFF);
            Wt[(n0 + 3) * 128 + (((kb + n0 + 3) & 15) << 3) + kin] = (u16)(v.y >> 16);
        }
        __syncthreads();
        for (int k0 = 0; k0 < 128; k0 += 32) {
            short8 af0, af1;
            if (AMODE == 0) {
                af0 = *(const short8*)(Ab + rb0 + kc + k0);
                af1 = *(const short8*)(Ab + rb1 + kc + k0);
            } else if (AMODE == 1) {
                af0 = cvt_frag(*(const float4*)(Af + rb0 + kc + k0),
                               *(const float4*)(Af + rb0 + kc + k0 + 4));
                af1 = cvt_frag(*(const float4*)(Af + rb1 + kc + k0),
                               *(const float4*)(Af + rb1 + kc + k0 + 4));
            } else {
                int kb4 = k0 + quad * 8;
                float4 A0 = *(const float4*)&As[kb4], A1 = *(const float4*)&As[kb4 + 4];
                float4 C0 = *(const float4*)&Cs[kb4], C1 = *(const float4*)&Cs[kb4 + 4];
                af0 = bn_frag(*(const short8*)(Ab + rb0 + k0), A0, A1, C0, C1);
                af1 = bn_frag(*(const short8*)(Ab + rb1 + k0), A0, A1, C0, C1);
            }
            if (!v0) af0 = (short8)(short)0;
            if (!v1) af1 = (short8)(short)0;
            const int kb = (k0 >> 3) + quad;
#pragma unroll
            for (int c = 0; c < 8; c++) {
                const int n = c * 16 + l16;
                short8 bf = *(const short8*)&Wt[n * 128 + (((kb + n) & 15) << 3)];
                acc[0][c] = __builtin_amdgcn_mfma_f32_16x16x32_bf16(af0, bf, acc[0][c], 0, 0, 0);
                acc[1][c] = __builtin_amdgcn_mfma_f32_16x16x32_bf16(af1, bf, acc[1][c], 0, 0, 0);
            }
        }
    }
#pragma unroll
    for (int g = 0; g < 2; g++) {
#pragma unroll
        for (int c = 0; c < 8; c++)
#pragma unroll
            for (int r = 0; r < 4; r++)
                tb[wave][quad * 4 + r][c * 16 + l16] = f2bf(acc[g][c][r]);
        asm volatile("s_waitcnt lgkmcnt(0)" ::: "memory");
#pragma unroll
        for (int j = 0; j < 4; j++) {
            int row_l = j * 4 + (lane >> 4);
            int row = rowt + g * 16 + row_l;
            if (row < M) {
                short8 vv = *(const short8*)&tb[wave][row_l][(lane & 15) * 8];
                *(short8*)(C + (size_t)row * 128 + (lane & 15) * 8) = vv;
            }
        }
        if (g == 0) asm volatile("s_waitcnt lgkmcnt(0)" ::: "memory");
    }
}

// ---------------- gather over CAP=16 buckets + overflow list ----------------
__global__ __launch_bounds__(256) void gather_fixed(
    const u16* __restrict__ src, const int* __restrict__ cnt,
    const int* __restrict__ col, const float* __restrict__ wgt,
    u16* __restrict__ dst, float* __restrict__ zp,
    const uint2* __restrict__ ovf, const int* __restrict__ ovfCnt, int nrows)
{
    if (zp && blockIdx.x == 0) zp[threadIdx.x] = 0.0f;
    int r = blockIdx.x * 4 + (threadIdx.x >> 6);
    if (r >= nrows) return;
    int lane = threadIdx.x & 63;
    int c = cnt[r];
    int cc = (c > CAP) ? CAP : c;
    int m = (lane < cc) ? col[(r << 4) + lane] : 0;
    const size_t lb = (size_t)lane * 2;
    float ax = 0.0f, ay = 0.0f;
    int j = 0;
    for (; j + 4 <= cc; j += 4) {
        int s0 = __shfl(m, j),     s1 = __shfl(m, j + 1);
        int s2 = __shfl(m, j + 2), s3 = __shfl(m, j + 3);
        unsigned int a = *(const unsigned int*)&src[(size_t)s0 * 128 + lb];
        unsigned int b = *(const unsigned int*)&src[(size_t)s1 * 128 + lb];
        unsigned int e = *(const unsigned int*)&src[(size_t)s2 * 128 + lb];
        unsigned int d = *(const unsigned int*)&src[(size_t)s3 * 128 + lb];
        ax += bf2f((u16)(a & 0xFFFF)) + bf2f((u16)(b & 0xFFFF))
            + bf2f((u16)(e & 0xFFFF)) + bf2f((u16)(d & 0xFFFF));
        ay += bf2f((u16)(a >> 16)) + bf2f((u16)(b >> 16))
            + bf2f((u16)(e >> 16)) + bf2f((u16)(d >> 16));
    }
    for (; j < cc; j++) {
        int s = __shfl(m, j);
        unsigned int v = *(const unsigned int*)&src[(size_t)s * 128 + lb];
        ax += bf2f((u16)(v & 0xFFFF));
        ay += bf2f((u16)(v >> 16));
    }
    if (c > CAP) {                       // rare (~16 rows): scan overflow list
        int nov = *ovfCnt; if (nov > OVF_MAX) nov = OVF_MAX;
        for (int i2 = 0; i2 < nov; i2++) {
            uint2 p = ovf[i2];
            if ((int)p.x == r) {
                unsigned int v = *(const unsigned int*)&src[(size_t)p.y * 128 + lb];
                ax += bf2f((u16)(v & 0xFFFF));
                ay += bf2f((u16)(v >> 16));
            }
        }
    }
    float w = wgt[r];
    unsigned int o = (unsigned int)f2bf(ax * w) | ((unsigned int)f2bf(ay * w) << 16);
    *(unsigned int*)&dst[(size_t)r * 128 + lb] = o;
}

// ---------------- BN stats over v = z[row][col] + bias[col] (z bf16) --------
__global__ __launch_bounds__(256) void bn_stats(
    const u16* __restrict__ z, const float* __restrict__ bias,
    float* __restrict__ gsum, float* __restrict__ gsq, int M)
{
    __shared__ float ssum[256], ssq[256];
    int col  = threadIdx.x & 127;
    int half = threadIdx.x >> 7;
    int base = blockIdx.x * 128;
    float bc = bias[col];
    float s = 0.0f, q = 0.0f;
    for (int r = half; r < 128; r += 2) {
        int row = base + r;
        if (row < M) {
            float v = bf2f(z[(size_t)row * 128 + col]) + bc;
            s += v; q += v * v;
        }
    }
    ssum[threadIdx.x] = s; ssq[threadIdx.x] = q;
    __syncthreads();
    if (half == 0) {
        atomAddF(&gsum[col], ssum[col] + ssum[col + 128]);
        atomAddF(&gsq[col],  ssq[col]  + ssq[col + 128]);
    }
}

// ---------------- MFMA classifier with fused BN on the A-path ---------------
__global__ __launch_bounds__(256) void classifier_mfma(
    const u16* __restrict__ Z, const float* __restrict__ Wc1,
    const float* __restrict__ bc1, const float* __restrict__ Wc2,
    const float* __restrict__ bc2, float* __restrict__ out, int M,
    const float* __restrict__ gsum, const float* __restrict__ gsq,
    const float* __restrict__ bias, const float* __restrict__ gam,
    const float* __restrict__ bet, float invM)
{
    __shared__ __attribute__((aligned(16))) u16 W1t[64 * 128];   // 16 KB
    __shared__ __attribute__((aligned(16))) u16 W2t[16 * 64];    // 2 KB
    __shared__ __attribute__((aligned(16))) u16 hs[128][72];     // 18.4 KB
    __shared__ __attribute__((aligned(16))) float As[128];
    __shared__ __attribute__((aligned(16))) float Cs[128];
    const int tid = threadIdx.x;
    if (tid < 128) {
        float mean = gsum[tid] * invM;
        float var  = gsq[tid] * invM - mean * mean;
        if (var < 0.0f) var = 0.0f;
        float sc = gam[tid] * rsqrtf(var + 1e-5f);
        As[tid] = sc;
        Cs[tid] = (bias[tid] - mean) * sc + bet[tid];
    }
    for (int i = tid; i < 64 * 128; i += 256) {   // i = k*64 + n
        int k = i >> 6, n = i & 63;
        int kb = k >> 3, kin = k & 7;
        W1t[n * 128 + (((kb + n) & 15) << 3) + kin] = f2bf(Wc1[i]);
    }
    for (int i = tid; i < 16 * 64; i += 256) {    // i = k*16 + n
        int k = i >> 4, n = i & 15;
        W2t[n * 64 + k] = (n < 10) ? f2bf(Wc2[k * 10 + n]) : (u16)0;
    }
    __syncthreads();

    const int wave = tid >> 6, lane = tid & 63;
    const int l16 = lane & 15, quad = lane >> 4;
    const int rowt = blockIdx.x * 128 + wave * 32;
    const int r0 = rowt + l16, r1 = rowt + 16 + l16;
    const bool v0 = r0 < M, v1 = r1 < M;
    const u16* a0p = Z + (size_t)(v0 ? r0 : 0) * 128 + quad * 8;
    const u16* a1p = Z + (size_t)(v1 ? r1 : 0) * 128 + quad * 8;

    float4v acc[2][4];
#pragma unroll
    for (int g = 0; g < 2; g++)
#pragma unroll
        for (int c = 0; c < 4; c++) acc[g][c] = (float4v)0.0f;

#pragma unroll
    for (int k0 = 0; k0 < 128; k0 += 32) {
        int kb4 = k0 + quad * 8;
        float4 A0 = *(const float4*)&As[kb4], A1 = *(const float4*)&As[kb4 + 4];
        float4 C0 = *(const float4*)&Cs[kb4], C1 = *(const float4*)&Cs[kb4 + 4];
        short8 af0 = bn_frag(*(const short8*)(a0p + k0), A0, A1, C0, C1);
        short8 af1 = bn_frag(*(const short8*)(a1p + k0), A0, A1, C0, C1);
        if (!v0) af0 = (short8)(short)0;
        if (!v1) af1 = (short8)(short)0;
        const int kb = (k0 >> 3) + quad;
#pragma unroll
        for (int c = 0; c < 4; c++) {
            const int n = c * 16 + l16;
            short8 bf = *(const short8*)&W1t[n * 128 + (((kb + n) & 15) << 3)];
            acc[0][c] = __builtin_amdgcn_mfma_f32_16x16x32_bf16(af0, bf, acc[0][c], 0, 0, 0);
            acc[1][c] = __builtin_amdgcn_mfma_f32_16x16x32_bf16(af1, bf, acc[1][c], 0, 0, 0);
        }
    }
#pragma unroll
    for (int g = 0; g < 2; g++)
#pragma unroll
        for (int c = 0; c < 4; c++) {
            float b = bc1[c * 16 + l16];
#pragma unroll
            for (int r = 0; r < 4; r++)
                hs[wave * 32 + g * 16 + quad * 4 + r][c * 16 + l16] =
                    f2bf(fmaxf(acc[g][c][r] + b, 0.0f));
        }
    asm volatile("s_waitcnt lgkmcnt(0)" ::: "memory");

    float4v a2[2];
    a2[0] = (float4v)0.0f; a2[1] = (float4v)0.0f;
#pragma unroll
    for (int k0 = 0; k0 < 64; k0 += 32) {
        short8 bf = *(const short8*)&W2t[l16 * 64 + k0 + quad * 8];
#pragma unroll
        for (int g = 0; g < 2; g++) {
            short8 af = *(const short8*)&hs[wave * 32 + g * 16 + l16][k0 + quad * 8];
            a2[g] = __builtin_amdgcn_mfma_f32_16x16x32_bf16(af, bf, a2[g], 0, 0, 0);
        }
    }
    if (l16 < 10) {
        float b2 = bc2[l16];
#pragma unroll
        for (int g = 0; g < 2; g++)
#pragma unroll
            for (int r = 0; r < 4; r++) {
                int row = rowt + g * 16 + quad * 4 + r;
                if (row < M) out[(size_t)row * 10 + l16] = a2[g][r] + b2;
            }
    }
}

// ---------------- launch ----------------------------------------------------
extern "C" void kernel_launch(void* const* d_in, const int* in_sizes, int n_in,
                              void* d_out, int out_size, void* d_ws, size_t ws_size,
                              hipStream_t stream)
{
    const int M   = N_NODES;
    const int NE  = N_EDGES;
    const int nnz = NNZ_C;

    const float* x   = (const float*)d_in[0];
    const int*  nidx = (const int*)d_in[1];
    const int*  eidx = nidx + nnz;
    const float* W1  = (const float*)d_in[2];
    const float* b1  = (const float*)d_in[3];
    const float* W2  = (const float*)d_in[4];
    const float* b2  = (const float*)d_in[5];
    const float* W3  = (const float*)d_in[6];
    const float* b3  = (const float*)d_in[7];
    const float* g1  = (const float*)d_in[8];
    const float* bt1 = (const float*)d_in[9];
    const float* g2  = (const float*)d_in[10];
    const float* bt2 = (const float*)d_in[11];
    const float* g3  = (const float*)d_in[12];
    const float* bt3 = (const float*)d_in[13];
    const float* Wc1 = (const float*)d_in[14];
    const float* bc1 = (const float*)d_in[15];
    const float* Wc2 = (const float*)d_in[16];
    const float* bc2 = (const float*)d_in[17];
    float* out = (float*)d_out;

    // ---- workspace carve-up ----
    const size_t SZH = (size_t)M * 128 * sizeof(u16);   // 25.6 MB
    char* ws = (char*)d_ws;
    u16* Y = (u16*)(ws);                     // GEMM output (bf16)
    u16* E = (u16*)(ws + SZH);               // edge features (bf16)
    u16* Z = (u16*)(ws + 2 * SZH);           // node agg, pre-BN (bf16)
    int* ib = (int*)(ws + 3 * SZH);
    int*   cb      = ib;                     // edge sizes / cursors [100000]
    int*   cd      = ib + 100000;            // node degrees / cursors
    int*   ovfCntB = ib + 200000;
    int*   ovfCntD = ib + 200001;
    int*   colB    = ib + 200016;            // 64-B aligned; [100000*16]
    int*   colD    = ib + 200016 + NE * CAP;
    uint2* ovfB    = (uint2*)(ib + 200016 + (NE + M) * CAP);
    uint2* ovfD    = ovfB + OVF_MAX;
    float* fb = (float*)(ovfD + OVF_MAX);
    float* Dinv = fb;
    float* Binv = fb + 100000;
    float* gsum = fb + 200000;               // [128]; gsq contiguous after
    float* gsq  = fb + 200128;
    u16* wbuf = (u16*)(fb + 200256);
    u16* W1b = wbuf;                         // 256*128 bf16
    u16* W2b = wbuf + 32768;                 // 128*128
    u16* W3b = wbuf + 49152;                 // 128*128

    const int ntiles       = (M + 127) / 128;
    const int stats_blocks = (M + 127) / 128;
    const int gather_blkN  = (M + 3) / 4;
    const int gather_blkE  = (NE + 3) / 4;
    const float invM = 1.0f / (float)M;

    // ---- index preprocessing ----
    hipMemsetAsync(cb, 0, 800008, stream);   // cb + cd + both overflow counters
    fill_direct<<<(nnz + 255) / 256, 256, 0, stream>>>(
        nidx, eidx, cb, cd, colB, colD, ovfB, ovfD, ovfCntB, ovfCntD, nnz);
    make_inv_kernel<<<(M + 255) / 256, 256, 0, stream>>>(cd, cb, Dinv, Binv, M);
    convert_w<<<64, 256, 0, stream>>>(W1, W2, W3, W1b, W2b, W3b);

    const float* bin[3]  = { b1, b2, b3 };
    const float* gin[3]  = { g1, g2, g3 };
    const float* btin[3] = { bt1, bt2, bt3 };
    const u16*   Wbf[3]  = { W1b, W2b, W3b };

    for (int L = 0; L < 3; L++) {
        if (L == 0)
            gemm_mfma<256, 1><<<ntiles, 256, 0, stream>>>(
                x, Wbf[0], Y, M, nullptr, nullptr, nullptr, nullptr, nullptr, 0.0f);
        else
            gemm_mfma<128, 2><<<ntiles, 256, 0, stream>>>(
                Z, Wbf[L], Y, M, gsum, gsq, bin[L - 1], gin[L - 1], btin[L - 1], invM);
        gather_fixed<<<gather_blkE, 256, 0, stream>>>(
            Y, cb, colB, Binv, E, nullptr, ovfB, ovfCntB, NE);
        gather_fixed<<<gather_blkN, 256, 0, stream>>>(
            E, cd, colD, Dinv, Z, gsum, ovfD, ovfCntD, M);
        bn_stats<<<stats_blocks, 256, 0, stream>>>(Z, bin[L], gsum, gsq, M);
    }

    classifier_mfma<<<ntiles, 256, 0, stream>>>(
        Z, Wc1, bc1, Wc2, bc2, out, M, gsum, gsq, bin[2], gin[2], btin[2], invM);
}